// Round 6
// baseline (660.326 us; speedup 1.0000x reference)
//
#include <hip/hip_runtime.h>
#include <hip/hip_fp16.h>
#include <math.h>

#define TB 256

typedef _Float16 half8v __attribute__((ext_vector_type(8)));
typedef float float4v __attribute__((ext_vector_type(4)));

static __device__ __forceinline__ unsigned f2o(float x) {
    unsigned b = __float_as_uint(x);
    return (b & 0x80000000u) ? ~b : (b | 0x80000000u);
}
static __device__ __forceinline__ float o2f(unsigned u) {
    return (u & 0x80000000u) ? __uint_as_float(u & 0x7FFFFFFFu) : __uint_as_float(~u);
}

static __device__ __forceinline__ int edge_src(const int* ei, int E, int e) {
    return (e < E) ? ei[e] : (e - E);
}
static __device__ __forceinline__ int edge_dst(const int* ei, int E, int e) {
    return (e < E) ? ei[E + e] : (e - E);
}

// ---------------- CSR build ----------------
__global__ void csr_count(const int* __restrict__ ei, int E, int Etot, int* __restrict__ cnt) {
    int e = blockIdx.x * blockDim.x + threadIdx.x;
    if (e >= Etot) return;
    atomicAdd(&cnt[edge_dst(ei, E, e)], 1);
}

__global__ __launch_bounds__(256) void scan_phase1(const int* __restrict__ cnt,
                                                   int* __restrict__ incl,
                                                   int* __restrict__ bsum, int n) {
    __shared__ int sdata[256];
    int t = threadIdx.x;
    int base = blockIdx.x * 256;
    int v = (base + t < n) ? cnt[base + t] : 0;
    for (int d = 1; d < 256; d <<= 1) {
        sdata[t] = v; __syncthreads();
        if (t >= d) v += sdata[t - d];
        __syncthreads();
    }
    if (base + t < n) incl[base + t] = v;
    if (t == 255) bsum[blockIdx.x] = v;
}

__global__ void scan_phase2(int* bsum, int nb) {
    __shared__ int sdata[256];
    int t = threadIdx.x;
    int v = (t < nb) ? bsum[t] : 0;
    for (int d = 1; d < 256; d <<= 1) {
        sdata[t] = v; __syncthreads();
        if (t >= d) v += sdata[t - d];
        __syncthreads();
    }
    if (t < nb) bsum[t] = v;
}

__global__ __launch_bounds__(256) void scan_phase3(const int* __restrict__ incl,
                                                   const int* __restrict__ bsum,
                                                   int* __restrict__ off, int n) {
    int i = blockIdx.x * 256 + threadIdx.x;
    if (i < n) off[i + 1] = incl[i] + (blockIdx.x ? bsum[blockIdx.x - 1] : 0);
    if (i == 0) off[0] = 0;
}

__global__ void csr_fill(const int* __restrict__ ei, int E, int Etot,
                         const int* __restrict__ off, int* __restrict__ cur,
                         int* __restrict__ esrc) {
    int e = blockIdx.x * blockDim.x + threadIdx.x;
    if (e >= Etot) return;
    int d = edge_dst(ei, E, e);
    int pos = atomicAdd(&cur[d], 1);
    esrc[off[d] + pos] = edge_src(ei, E, e);
}

// ---------------- prep ----------------
__global__ void cast_f2h(const float* __restrict__ in, __half* __restrict__ out, int n) {
    int i2 = (blockIdx.x * blockDim.x + threadIdx.x) * 2;
    if (i2 + 1 < n) {
        float2 v = *(const float2*)(in + i2);
        *(__half2*)(out + i2) = __floats2half2_rn(v.x, v.y);
    } else if (i2 < n) {
        out[i2] = __float2half(in[i2]);
    }
}

// ws[h*K+k] = sum_c W[k][h*C+c]*a_s[h][c]; wd likewise (fp32)
__global__ void make_ws(const float* __restrict__ W, const float* __restrict__ a_s,
                        const float* __restrict__ a_d, float* __restrict__ ws,
                        float* __restrict__ wd, int K, int H, int C) {
    int i = blockIdx.x * blockDim.x + threadIdx.x;
    if (i >= H * K) return;
    int h = i / K, k = i % K;
    const float* wrow = W + (size_t)k * H * C + h * C;
    float s = 0.f, d = 0.f;
    for (int c = 0; c < C; ++c) {
        s += wrow[c] * a_s[h * C + c];
        d += wrow[c] * a_d[h * C + c];
    }
    ws[i] = s;
    wd[i] = d;
}

// WT[c][h*K+k] = W[k][h*C+c]  (fp16), WT is [C][H*K]
__global__ void make_wstackT(const float* __restrict__ W, __half* __restrict__ WT,
                             int K, int H, int C) {
    int i = blockIdx.x * blockDim.x + threadIdx.x;
    if (i >= K * H * C) return;
    int c = i / (H * K);
    int rem = i % (H * K);
    int h = rem / K, k = rem % K;
    WT[i] = __float2half(W[(size_t)k * H * C + h * C + c]);
}

// ---------------- scores directly from A: es[n][h] = A[n] . ws[h] -----------
template <int K, int H>
__global__ __launch_bounds__(256) void scores_from_A(const __half* __restrict__ A,
                                                     const float* __restrict__ ws,
                                                     const float* __restrict__ wd,
                                                     float* __restrict__ es,
                                                     float* __restrict__ ed, int N) {
    constexpr int VPL = K / 64;
    int n = (blockIdx.x * blockDim.x + threadIdx.x) >> 6;
    int lane = threadIdx.x & 63;
    if (n >= N) return;
    float a[VPL];
    const __half* row = A + (size_t)n * K + lane * VPL;
    if constexpr (VPL == 2) {
        __half2 r = *(const __half2*)row;
        a[0] = __low2float(r);
        a[1] = __high2float(r);
    } else {
        a[0] = __half2float(row[0]);
    }
    float s[H], d[H];
#pragma unroll
    for (int h = 0; h < H; ++h) {
        s[h] = 0.f; d[h] = 0.f;
#pragma unroll
        for (int v = 0; v < VPL; ++v) {
            s[h] += a[v] * ws[h * K + lane * VPL + v];
            d[h] += a[v] * wd[h * K + lane * VPL + v];
        }
    }
#pragma unroll
    for (int o = 1; o < 64; o <<= 1) {
#pragma unroll
        for (int h = 0; h < H; ++h) {
            s[h] += __shfl_xor(s[h], o);
            d[h] += __shfl_xor(d[h], o);
        }
    }
    if (lane == 0) {
#pragma unroll
        for (int h = 0; h < H; ++h) {
            es[(size_t)n * H + h] = s[h];
            ed[(size_t)n * H + h] = d[h];
        }
    }
}

// ---------------- fused softmax + pre-projection aggregation -----------------
// z[n][h*K+k] = (1/(den_h*H)) * sum_e alpha_eh * A[src][k]
template <int K, int H>
__global__ __launch_bounds__(256) void gat_gather_z(const __half* __restrict__ A,
                                                    const float* __restrict__ es,
                                                    const float* __restrict__ ed,
                                                    const int* __restrict__ off,
                                                    const int* __restrict__ esrc,
                                                    __half* __restrict__ z, int N) {
    constexpr int VPL = K / 64;
    int n = (blockIdx.x * blockDim.x + threadIdx.x) >> 6;
    int lane = threadIdx.x & 63;
    if (n >= N) return;
    int j0 = off[n], j1 = off[n + 1];

    float ed_h = (lane < H) ? ed[(size_t)n * H + lane] : 0.f;

    float m_h = -INFINITY;
    for (int j = j0; j < j1; ++j) {
        int s = esrc[j];
        if (lane < H) {
            float v = es[(size_t)s * H + lane] + ed_h;
            v = (v > 0.f) ? v : 0.2f * v;
            m_h = fmaxf(m_h, v);
        }
    }

    float acc[H][VPL];
#pragma unroll
    for (int h = 0; h < H; ++h)
#pragma unroll
        for (int v = 0; v < VPL; ++v) acc[h][v] = 0.f;
    float den_h = 0.f;
    for (int j = j0; j < j1; ++j) {
        int s = esrc[j];
        float pm = 0.f;
        if (lane < H) {
            float v = es[(size_t)s * H + lane] + ed_h;
            v = (v > 0.f) ? v : 0.2f * v;
            pm = expf(v - m_h);
            den_h += pm;
        }
        float a[VPL];
        const __half* row = A + (size_t)s * K + lane * VPL;
        if constexpr (VPL == 2) {
            __half2 r = *(const __half2*)row;
            a[0] = __low2float(r);
            a[1] = __high2float(r);
        } else {
            a[0] = __half2float(row[0]);
        }
#pragma unroll
        for (int h = 0; h < H; ++h) {
            float al = __shfl(pm, h);
#pragma unroll
            for (int v = 0; v < VPL; ++v) acc[h][v] += al * a[v];
        }
    }

#pragma unroll
    for (int h = 0; h < H; ++h) {
        float inv = 1.f / ((__shfl(den_h, h) + 1e-16f) * H);
        __half* dst = z + (size_t)n * (H * K) + h * K + lane * VPL;
        if constexpr (VPL == 2) {
            *(__half2*)dst = __floats2half2_rn(acc[h][0] * inv, acc[h][1] * inv);
        } else {
            dst[0] = __float2half(acc[h][0] * inv);
        }
    }
}

// ---------------- K-tiled MFMA GEMM: C[M,Nout] = A[M,KK] @ BT[Nout,KK]^T -----
// +bias (per output col), optional relu. A,BT fp16; OUTT = __half or float.
template <int KK, typename OUTT, bool RELU>
__global__ __launch_bounds__(256) void gemm_kt(const __half* __restrict__ A,
                                               const __half* __restrict__ BT,
                                               const float* __restrict__ bias,
                                               OUTT* __restrict__ C,
                                               int M, int Nout) {
    __shared__ __align__(16) __half As[64 * 72];
    __shared__ __align__(16) __half Bs[64 * 72];
    int tid = threadIdx.x;
    int bm = blockIdx.y * 64, bn = blockIdx.x * 64;
    int wv = tid >> 6, l = tid & 63, lr = l & 15, g = l >> 4;
    float4v acc[4] = {{0.f, 0.f, 0.f, 0.f}, {0.f, 0.f, 0.f, 0.f},
                      {0.f, 0.f, 0.f, 0.f}, {0.f, 0.f, 0.f, 0.f}};
    for (int kc = 0; kc < KK; kc += 64) {
        __syncthreads();
        for (int idx = tid; idx < 512; idx += 256) {
            int row = idx >> 3, ko = (idx & 7) * 8;
            uint4 v = make_uint4(0u, 0u, 0u, 0u);
            int gr = bm + row;
            if (gr < M) v = *(const uint4*)(A + (size_t)gr * KK + kc + ko);
            *(uint4*)(&As[row * 72 + ko]) = v;
            uint4 wvv = *(const uint4*)(BT + (size_t)(bn + row) * KK + kc + ko);
            *(uint4*)(&Bs[row * 72 + ko]) = wvv;
        }
        __syncthreads();
#pragma unroll
        for (int k0 = 0; k0 < 64; k0 += 32) {
            half8v af = *reinterpret_cast<const half8v*>(&As[(16 * wv + lr) * 72 + k0 + 8 * g]);
#pragma unroll
            for (int nt = 0; nt < 4; ++nt) {
                half8v bf = *reinterpret_cast<const half8v*>(&Bs[(nt * 16 + lr) * 72 + k0 + 8 * g]);
                acc[nt] = __builtin_amdgcn_mfma_f32_16x16x32_f16(af, bf, acc[nt], 0, 0, 0);
            }
        }
    }
#pragma unroll
    for (int nt = 0; nt < 4; ++nt) {
        float b = bias[bn + nt * 16 + lr];
#pragma unroll
        for (int r = 0; r < 4; ++r) {
            int grow = bm + 16 * wv + 4 * g + r;
            if (grow < M) {
                float c = acc[nt][r] + b;
                if (RELU) c = fmaxf(c, 0.f);
                if constexpr (sizeof(OUTT) == 2)
                    C[(size_t)grow * Nout + bn + nt * 16 + lr] = __float2half(c);
                else
                    C[(size_t)grow * Nout + bn + nt * 16 + lr] = c;
            }
        }
    }
}

// ---------------- fp32 gather for decoder-0 (16-row table) -> fp16 out -------
__global__ __launch_bounds__(256) void gat_gather_d0(const float* __restrict__ hsrc,
                                                     const float* __restrict__ es,
                                                     const float* __restrict__ ed,
                                                     const int* __restrict__ off,
                                                     const int* __restrict__ esrc,
                                                     const int* __restrict__ rmap,
                                                     const float* __restrict__ bias,
                                                     __half* __restrict__ out, int N) {
    int n = (blockIdx.x * blockDim.x + threadIdx.x) >> 6;
    int lane = threadIdx.x & 63;
    if (n >= N) return;
    int j0 = off[n], j1 = off[n + 1];
    float ed_h = (lane == 0) ? ed[n] : 0.f;
    float m_h = -INFINITY;
    for (int j = j0; j < j1; ++j) {
        int s = esrc[j];
        if (lane == 0) {
            float v = es[s] + ed_h;
            v = (v > 0.f) ? v : 0.2f * v;
            m_h = fmaxf(m_h, v);
        }
    }
    float acc = 0.f, den_h = 0.f;
    for (int j = j0; j < j1; ++j) {
        int s = esrc[j];
        float pm = 0.f;
        if (lane == 0) {
            float v = es[s] + ed_h;
            v = (v > 0.f) ? v : 0.2f * v;
            pm = expf(v - m_h);
            den_h += pm;
        }
        float a = __shfl(pm, 0);
        acc += a * hsrc[(size_t)rmap[s] * 64 + lane];
    }
    float dv = __shfl(den_h, 0) + 1e-16f;
    float o = acc / dv + bias[lane];
    o = fmaxf(o, 0.f);
    out[(size_t)n * 64 + lane] = __float2half(o);
}

// ---------------- pooling ----------------
__global__ __launch_bounds__(256) void gate_kernel(const __half* __restrict__ h,
                                                   const float* __restrict__ w1,
                                                   const float* __restrict__ b1,
                                                   const float* __restrict__ w2,
                                                   const float* __restrict__ b2,
                                                   float* __restrict__ gate, int N) {
    int n = (blockIdx.x * blockDim.x + threadIdx.x) >> 6;
    int lane = threadIdx.x & 63;
    if (n >= N) return;
    float hv = __half2float(h[(size_t)n * 64 + lane]);
    float t = b1[lane];
    for (int c = 0; c < 64; ++c) t += __shfl(hv, c) * w1[c * 64 + lane];
    t = fmaxf(t, 0.f);
    float g = t * w2[lane];
#pragma unroll
    for (int o = 32; o; o >>= 1) g += __shfl_xor(g, o);
    g += b2[0];
    if (lane == 0) gate[n] = g;
}

__global__ __launch_bounds__(256) void gmax_kernel(const float* __restrict__ gate,
                                                   const int* __restrict__ batch,
                                                   unsigned* __restrict__ gm, int N) {
    __shared__ unsigned smax[16];
    int t = threadIdx.x;
    if (t < 16) smax[t] = 0u;
    __syncthreads();
    for (int i = blockIdx.x * blockDim.x + t; i < N; i += gridDim.x * blockDim.x)
        atomicMax(&smax[batch[i]], f2o(gate[i]));
    __syncthreads();
    if (t < 16 && smax[t]) atomicMax(&gm[t], smax[t]);
}

__global__ __launch_bounds__(256) void pool_p(const float* __restrict__ gate,
                                              const unsigned* __restrict__ gm,
                                              const int* __restrict__ batch,
                                              float* __restrict__ pg,
                                              float* __restrict__ gden, int N) {
    __shared__ float part[16];
    int t = threadIdx.x;
    if (t < 16) part[t] = 0.f;
    __syncthreads();
    int n = blockIdx.x * blockDim.x + t;
    if (n < N) {
        int b = batch[n];
        unsigned u = gm[b];
        float mf = u ? o2f(u) : 0.f;
        float p = expf(gate[n] - mf);
        pg[n] = p;
        atomicAdd(&part[b], p);
    }
    __syncthreads();
    if (t < 16 && part[t] != 0.f) atomicAdd(&gden[t], part[t]);
}

#define NODES_PER_WAVE 128
__global__ __launch_bounds__(256) void pool_sum(const __half* __restrict__ h,
                                                const float* __restrict__ pg,
                                                const int* __restrict__ batch,
                                                float* __restrict__ pooled, int N) {
    int w = (blockIdx.x * blockDim.x + threadIdx.x) >> 6;
    int lane = threadIdx.x & 63;
    int start = w * NODES_PER_WAVE;
    if (start >= N) return;
    int curg = batch[start];
    float acc = 0.f;
    for (int i = 0; i < NODES_PER_WAVE; ++i) {
        int n = start + i;
        if (n >= N) break;
        int g = batch[n];
        if (g != curg) {
            atomicAdd(&pooled[curg * 64 + lane], acc);
            acc = 0.f;
            curg = g;
        }
        acc += pg[n] * __half2float(h[(size_t)n * 64 + lane]);
    }
    atomicAdd(&pooled[curg * 64 + lane], acc);
}

__global__ void dec_prep(const float* __restrict__ pooled, const float* __restrict__ gden,
                         const float* __restrict__ Wd0, const float* __restrict__ asd,
                         const float* __restrict__ add, float* __restrict__ hd016,
                         float* __restrict__ es16, float* __restrict__ ed16) {
    int g = blockIdx.x;
    int lane = threadIdx.x;
    float pn = pooled[g * 64 + lane] / (gden[g] + 1e-16f);
    float o = 0.f;
    for (int c = 0; c < 64; ++c) o += __shfl(pn, c) * Wd0[c * 64 + lane];
    hd016[g * 64 + lane] = o;
    float s = o * asd[lane], d = o * add[lane];
#pragma unroll
    for (int off = 32; off; off >>= 1) {
        s += __shfl_xor(s, off);
        d += __shfl_xor(d, off);
    }
    if (lane == 0) {
        es16[g] = s;
        ed16[g] = d;
    }
}

__global__ void expand_scores(const int* __restrict__ batch,
                              const float* __restrict__ es16,
                              const float* __restrict__ ed16,
                              float* __restrict__ esd,
                              float* __restrict__ edd, int N) {
    int n = blockIdx.x * blockDim.x + threadIdx.x;
    if (n >= N) return;
    int g = batch[n];
    esd[n] = es16[g];
    edd[n] = ed16[g];
}

// ---------------- host ----------------
static inline int cdiv(int a, int b) { return (a + b - 1) / b; }

extern "C" void kernel_launch(void* const* d_in, const int* in_sizes, int n_in,
                              void* d_out, int out_size, void* d_ws, size_t ws_size,
                              hipStream_t stream) {
    const float* x      = (const float*)d_in[0];
    const int*   ei     = (const int*)  d_in[1];
    const int*   batch  = (const int*)  d_in[2];
    const float* W_e0   = (const float*)d_in[3];
    const float* a_s_e0 = (const float*)d_in[4];
    const float* a_d_e0 = (const float*)d_in[5];
    const float* b_e0   = (const float*)d_in[6];
    const float* W_e1   = (const float*)d_in[7];
    const float* a_s_e1 = (const float*)d_in[8];
    const float* a_d_e1 = (const float*)d_in[9];
    const float* b_e1   = (const float*)d_in[10];
    const float* W_d0   = (const float*)d_in[11];
    const float* a_s_d0 = (const float*)d_in[12];
    const float* a_d_d0 = (const float*)d_in[13];
    const float* b_d0   = (const float*)d_in[14];
    const float* W_d1   = (const float*)d_in[15];
    const float* a_s_d1 = (const float*)d_in[16];
    const float* a_d_d1 = (const float*)d_in[17];
    const float* b_d1   = (const float*)d_in[18];
    const float* g_w1   = (const float*)d_in[19];
    const float* g_b1   = (const float*)d_in[20];
    const float* g_w2   = (const float*)d_in[21];
    const float* g_b2   = (const float*)d_in[22];

    const int N    = in_sizes[2];
    const int E    = in_sizes[1] / 2;
    const int Etot = E + N;
    const int Din  = in_sizes[0] / N;  // 128

    char* w = (char*)d_ws;
    size_t o = 0;
    auto alloc = [&](size_t bytes) -> void* {
        void* p = w + o;
        o = (o + bytes + 255) & ~(size_t)255;
        return p;
    };
    __half*   z      = (__half*)  alloc((size_t)N * 1024 * 2);  // largest z (enc0)
    __half*   x16    = (__half*)  alloc((size_t)N * Din * 2);
    __half*   bufA   = (__half*)  alloc((size_t)N * 64 * 2);
    __half*   bufB   = (__half*)  alloc((size_t)N * 64 * 2);
    float*    ws_e0  = (float*)   alloc(8 * 128 * 4);
    float*    wd_e0  = (float*)   alloc(8 * 128 * 4);
    float*    ws_e1  = (float*)   alloc(8 * 64 * 4);
    float*    wd_e1  = (float*)   alloc(8 * 64 * 4);
    float*    ws_d1  = (float*)   alloc(64 * 4);
    float*    wd_d1  = (float*)   alloc(64 * 4);
    __half*   wst_e0 = (__half*)  alloc((size_t)64 * 1024 * 2);
    __half*   wst_e1 = (__half*)  alloc((size_t)64 * 512 * 2);
    __half*   wst_d1 = (__half*)  alloc((size_t)128 * 64 * 2);
    float*    es     = (float*)   alloc((size_t)N * 8 * 4);
    float*    ed     = (float*)   alloc((size_t)N * 8 * 4);
    float*    gate   = (float*)   alloc((size_t)N * 4);
    float*    pg     = (float*)   alloc((size_t)N * 4);
    int*      off    = (int*)     alloc((size_t)(N + 1) * 4);
    int*      cnt    = (int*)     alloc((size_t)N * 4);
    int*      esrc   = (int*)     alloc((size_t)Etot * 4);
    int*      bsum   = (int*)     alloc(256 * 4);
    unsigned* gm     = (unsigned*)alloc(16 * 4);
    float*    gden   = (float*)   alloc(16 * 4);
    float*    pooled = (float*)   alloc(16 * 64 * 4);
    float*    hd016  = (float*)   alloc(16 * 64 * 4);
    float*    es16   = (float*)   alloc(16 * 4);
    float*    ed16   = (float*)   alloc(16 * 4);
    (void)ws_size; (void)n_in; (void)out_size;

    float* esd = gate;  // dec0 per-node scores (reuse)
    float* edd = pg;

    const int nodeWaveGrid = cdiv(N, 4);
    const int edgeGrid     = cdiv(Etot, TB);
    const int scanBlocks   = cdiv(N, 256);

    // ---- CSR ----
    hipMemsetAsync(cnt, 0, (size_t)N * 4, stream);
    csr_count<<<edgeGrid, TB, 0, stream>>>(ei, E, Etot, cnt);
    scan_phase1<<<scanBlocks, 256, 0, stream>>>(cnt, esrc /*temp incl*/, bsum, N);
    scan_phase2<<<1, 256, 0, stream>>>(bsum, scanBlocks);
    scan_phase3<<<scanBlocks, 256, 0, stream>>>(esrc, bsum, off, N);
    hipMemsetAsync(cnt, 0, (size_t)N * 4, stream);
    csr_fill<<<edgeGrid, TB, 0, stream>>>(ei, E, Etot, off, cnt, esrc);

    // ---- prep: casts + folded weights ----
    cast_f2h<<<cdiv(N * Din / 2, TB), TB, 0, stream>>>(x, x16, N * Din);
    make_ws<<<cdiv(8 * 128, TB), TB, 0, stream>>>(W_e0, a_s_e0, a_d_e0, ws_e0, wd_e0, 128, 8, 64);
    make_ws<<<cdiv(8 * 64, TB), TB, 0, stream>>>(W_e1, a_s_e1, a_d_e1, ws_e1, wd_e1, 64, 8, 64);
    make_ws<<<1, TB, 0, stream>>>(W_d1, a_s_d1, a_d_d1, ws_d1, wd_d1, 64, 1, 128);
    make_wstackT<<<cdiv(64 * 1024, TB), TB, 0, stream>>>(W_e0, wst_e0, 128, 8, 64);
    make_wstackT<<<cdiv(64 * 512, TB), TB, 0, stream>>>(W_e1, wst_e1, 64, 8, 64);
    make_wstackT<<<cdiv(128 * 64, TB), TB, 0, stream>>>(W_d1, wst_d1, 64, 1, 128);

    // ---- encoder layer 0 (H=8, relu) ----
    scores_from_A<128, 8><<<nodeWaveGrid, TB, 0, stream>>>(x16, ws_e0, wd_e0, es, ed, N);
    gat_gather_z<128, 8><<<nodeWaveGrid, TB, 0, stream>>>(x16, es, ed, off, esrc, z, N);
    {
        dim3 grid(1, cdiv(N, 64));
        gemm_kt<1024, __half, true><<<grid, TB, 0, stream>>>(z, wst_e0, b_e0, bufA, N, 64);
    }

    // ---- encoder layer 1 (H=8, no relu) ----
    scores_from_A<64, 8><<<nodeWaveGrid, TB, 0, stream>>>(bufA, ws_e1, wd_e1, es, ed, N);
    gat_gather_z<64, 8><<<nodeWaveGrid, TB, 0, stream>>>(bufA, es, ed, off, esrc, z, N);
    {
        dim3 grid(1, cdiv(N, 64));
        gemm_kt<512, __half, false><<<grid, TB, 0, stream>>>(z, wst_e1, b_e1, bufB, N, 64);
    }

    // ---- pooling ----
    hipMemsetAsync(gm, 0, 16 * 4, stream);
    hipMemsetAsync(gden, 0, 16 * 4, stream);
    hipMemsetAsync(pooled, 0, 16 * 64 * 4, stream);
    gate_kernel<<<nodeWaveGrid, TB, 0, stream>>>(bufB, g_w1, g_b1, g_w2, g_b2, gate, N);
    gmax_kernel<<<256, TB, 0, stream>>>(gate, batch, gm, N);
    pool_p<<<cdiv(N, TB), TB, 0, stream>>>(gate, gm, batch, pg, gden, N);
    pool_sum<<<cdiv(cdiv(N, NODES_PER_WAVE), 4), TB, 0, stream>>>(bufB, pg, batch, pooled, N);
    dec_prep<<<16, 64, 0, stream>>>(pooled, gden, W_d0, a_s_d0, a_d_d0, hd016, es16, ed16);
    expand_scores<<<cdiv(N, TB), TB, 0, stream>>>(batch, es16, ed16, esd, edd, N);

    // ---- decoder layer 0 (H=1, relu): gather from 16-row hd016 via batch[src] ----
    gat_gather_d0<<<nodeWaveGrid, TB, 0, stream>>>(
        hd016, esd, edd, off, esrc, batch, b_d0, bufA, N);

    // ---- decoder layer 1 (H=1, C=128, no relu) -> d_out ----
    scores_from_A<64, 1><<<nodeWaveGrid, TB, 0, stream>>>(bufA, ws_d1, wd_d1, es, ed, N);
    gat_gather_z<64, 1><<<nodeWaveGrid, TB, 0, stream>>>(bufA, es, ed, off, esrc, z, N);
    {
        dim3 grid(2, cdiv(N, 64));
        gemm_kt<64, float, false><<<grid, TB, 0, stream>>>(z, wst_d1, b_d1, (float*)d_out, N, 128);
    }
}

// Round 7
// 586.582 us; speedup vs baseline: 1.1257x; 1.1257x over previous
//
#include <hip/hip_runtime.h>
#include <hip/hip_fp16.h>
#include <math.h>

#define TB 256

typedef _Float16 half8v __attribute__((ext_vector_type(8)));
typedef float float4v __attribute__((ext_vector_type(4)));

static __device__ __forceinline__ unsigned f2o(float x) {
    unsigned b = __float_as_uint(x);
    return (b & 0x80000000u) ? ~b : (b | 0x80000000u);
}
static __device__ __forceinline__ float o2f(unsigned u) {
    return (u & 0x80000000u) ? __uint_as_float(u & 0x7FFFFFFFu) : __uint_as_float(~u);
}

static __device__ __forceinline__ int edge_src(const int* ei, int E, int e) {
    return (e < E) ? ei[e] : (e - E);
}
static __device__ __forceinline__ int edge_dst(const int* ei, int E, int e) {
    return (e < E) ? ei[E + e] : (e - E);
}

// ---------------- CSR build ----------------
__global__ void csr_count(const int* __restrict__ ei, int E, int Etot, int* __restrict__ cnt) {
    int e = blockIdx.x * blockDim.x + threadIdx.x;
    if (e >= Etot) return;
    atomicAdd(&cnt[edge_dst(ei, E, e)], 1);
}

__global__ __launch_bounds__(256) void scan_phase1(const int* __restrict__ cnt,
                                                   int* __restrict__ incl,
                                                   int* __restrict__ bsum, int n) {
    __shared__ int sdata[256];
    int t = threadIdx.x;
    int base = blockIdx.x * 256;
    int v = (base + t < n) ? cnt[base + t] : 0;
    for (int d = 1; d < 256; d <<= 1) {
        sdata[t] = v; __syncthreads();
        if (t >= d) v += sdata[t - d];
        __syncthreads();
    }
    if (base + t < n) incl[base + t] = v;
    if (t == 255) bsum[blockIdx.x] = v;
}

__global__ void scan_phase2(int* bsum, int nb) {
    __shared__ int sdata[256];
    int t = threadIdx.x;
    int v = (t < nb) ? bsum[t] : 0;
    for (int d = 1; d < 256; d <<= 1) {
        sdata[t] = v; __syncthreads();
        if (t >= d) v += sdata[t - d];
        __syncthreads();
    }
    if (t < nb) bsum[t] = v;
}

__global__ __launch_bounds__(256) void scan_phase3(const int* __restrict__ incl,
                                                   const int* __restrict__ bsum,
                                                   int* __restrict__ off, int n) {
    int i = blockIdx.x * 256 + threadIdx.x;
    if (i < n) off[i + 1] = incl[i] + (blockIdx.x ? bsum[blockIdx.x - 1] : 0);
    if (i == 0) off[0] = 0;
}

__global__ void csr_fill(const int* __restrict__ ei, int E, int Etot,
                         const int* __restrict__ off, int* __restrict__ cur,
                         int* __restrict__ esrc) {
    int e = blockIdx.x * blockDim.x + threadIdx.x;
    if (e >= Etot) return;
    int d = edge_dst(ei, E, e);
    int pos = atomicAdd(&cur[d], 1);
    esrc[off[d] + pos] = edge_src(ei, E, e);
}

// ---------------- prep ----------------
__global__ void cast_f2h(const float* __restrict__ in, __half* __restrict__ out, int n) {
    int i2 = (blockIdx.x * blockDim.x + threadIdx.x) * 2;
    if (i2 + 1 < n) {
        float2 v = *(const float2*)(in + i2);
        *(__half2*)(out + i2) = __floats2half2_rn(v.x, v.y);
    } else if (i2 < n) {
        out[i2] = __float2half(in[i2]);
    }
}

// ws[h*K+k] = sum_c W[k][h*C+c]*a_s[h][c]; wd likewise (fp32)
__global__ void make_ws(const float* __restrict__ W, const float* __restrict__ a_s,
                        const float* __restrict__ a_d, float* __restrict__ ws,
                        float* __restrict__ wd, int K, int H, int C) {
    int i = blockIdx.x * blockDim.x + threadIdx.x;
    if (i >= H * K) return;
    int h = i / K, k = i % K;
    const float* wrow = W + (size_t)k * H * C + h * C;
    float s = 0.f, d = 0.f;
    for (int c = 0; c < C; ++c) {
        s += wrow[c] * a_s[h * C + c];
        d += wrow[c] * a_d[h * C + c];
    }
    ws[i] = s;
    wd[i] = d;
}

// WT[nn][kk] = W[kk][nn], fp16 (for post-projection GEMM)
__global__ void transpose_cast(const float* __restrict__ W, __half* __restrict__ WT,
                               int K, int N) {
    int i = blockIdx.x * blockDim.x + threadIdx.x;
    if (i >= N * K) return;
    int nn = i / K, kk = i % K;
    WT[i] = __float2half(W[kk * N + nn]);
}

// WT[c][h*K+k] = W[k][h*C+c]  (fp16), WT is [C][H*K] (for z-path GEMM)
__global__ void make_wstackT(const float* __restrict__ W, __half* __restrict__ WT,
                             int K, int H, int C) {
    int i = blockIdx.x * blockDim.x + threadIdx.x;
    if (i >= K * H * C) return;
    int c = i / (H * K);
    int rem = i % (H * K);
    int h = rem / K, k = rem % K;
    WT[i] = __float2half(W[(size_t)k * H * C + h * C + c]);
}

// ---------------- MFMA GEMM: C[M,N] = A[M,K] @ B[K,N] (post-projection) -----
template <int K>
__global__ __launch_bounds__(256) void gemm_mfma(const __half* __restrict__ A,
                                                 const __half* __restrict__ BT,
                                                 __half* __restrict__ C,
                                                 int M, int N) {
    constexpr int KP = K + 8;
    __shared__ __align__(16) __half As[64 * KP];
    __shared__ __align__(16) __half Bs[64 * KP];
    int tid = threadIdx.x;
    int bm = blockIdx.y * 64, bn = blockIdx.x * 64;
    constexpr int LPR = K / 8;
    for (int idx = tid; idx < 64 * LPR; idx += 256) {
        int row = idx / LPR, koff = (idx % LPR) * 8;
        uint4 v = make_uint4(0u, 0u, 0u, 0u);
        int gr = bm + row;
        if (gr < M) v = *(const uint4*)(A + (size_t)gr * K + koff);
        *(uint4*)(&As[row * KP + koff]) = v;
        uint4 wv = *(const uint4*)(BT + (size_t)(bn + row) * K + koff);
        *(uint4*)(&Bs[row * KP + koff]) = wv;
    }
    __syncthreads();
    int wv_ = tid >> 6, l = tid & 63;
    int lr = l & 15, g = l >> 4;
    float4v acc[4] = {{0.f, 0.f, 0.f, 0.f}, {0.f, 0.f, 0.f, 0.f},
                      {0.f, 0.f, 0.f, 0.f}, {0.f, 0.f, 0.f, 0.f}};
    const __half* ap = &As[(16 * wv_ + lr) * KP + 8 * g];
    const __half* bp = &Bs[lr * KP + 8 * g];
#pragma unroll
    for (int k0 = 0; k0 < K; k0 += 32) {
        half8v af = *reinterpret_cast<const half8v*>(ap + k0);
#pragma unroll
        for (int nt = 0; nt < 4; ++nt) {
            half8v bf = *reinterpret_cast<const half8v*>(bp + nt * 16 * KP + k0);
            acc[nt] = __builtin_amdgcn_mfma_f32_16x16x32_f16(af, bf, acc[nt], 0, 0, 0);
        }
    }
#pragma unroll
    for (int nt = 0; nt < 4; ++nt) {
#pragma unroll
        for (int r = 0; r < 4; ++r) {
            int grow = bm + 16 * wv_ + 4 * g + r;
            if (grow < M)
                C[(size_t)grow * N + bn + nt * 16 + lr] = __float2half(acc[nt][r]);
        }
    }
}

// ---------------- scores directly from A: es[n][h] = A[n] . ws[h] -----------
template <int K, int H>
__global__ __launch_bounds__(256) void scores_from_A(const __half* __restrict__ A,
                                                     const float* __restrict__ ws,
                                                     const float* __restrict__ wd,
                                                     float* __restrict__ es,
                                                     float* __restrict__ ed, int N) {
    constexpr int VPL = K / 64;
    int n = (blockIdx.x * blockDim.x + threadIdx.x) >> 6;
    int lane = threadIdx.x & 63;
    if (n >= N) return;
    float a[VPL];
    const __half* row = A + (size_t)n * K + lane * VPL;
    if constexpr (VPL == 2) {
        __half2 r = *(const __half2*)row;
        a[0] = __low2float(r);
        a[1] = __high2float(r);
    } else {
        a[0] = __half2float(row[0]);
    }
    float s[H], d[H];
#pragma unroll
    for (int h = 0; h < H; ++h) {
        s[h] = 0.f; d[h] = 0.f;
#pragma unroll
        for (int v = 0; v < VPL; ++v) {
            s[h] += a[v] * ws[h * K + lane * VPL + v];
            d[h] += a[v] * wd[h * K + lane * VPL + v];
        }
    }
#pragma unroll
    for (int o = 1; o < 64; o <<= 1) {
#pragma unroll
        for (int h = 0; h < H; ++h) {
            s[h] += __shfl_xor(s[h], o);
            d[h] += __shfl_xor(d[h], o);
        }
    }
    if (lane == 0) {
#pragma unroll
        for (int h = 0; h < H; ++h) {
            es[(size_t)n * H + h] = s[h];
            ed[(size_t)n * H + h] = d[h];
        }
    }
}

// ------- FUSED single-pass softmax (no max-sub) + aggregation from fp16 h ----
template <int H, int C, bool RELU, typename OUT>
__global__ __launch_bounds__(256) void gat_gather_h(const __half* __restrict__ hsrc,
                                                    const float* __restrict__ es,
                                                    const float* __restrict__ ed,
                                                    const int* __restrict__ off,
                                                    const int* __restrict__ esrc,
                                                    const float* __restrict__ bias,
                                                    OUT* __restrict__ out, int N) {
    constexpr int HC = H * C;
    constexpr int VPL = HC / 64;
    constexpr int LPH = 64 / H;
    int n = (blockIdx.x * blockDim.x + threadIdx.x) >> 6;
    int lane = threadIdx.x & 63;
    if (n >= N) return;
    int hd = lane / LPH;
    int j0 = off[n], j1 = off[n + 1];

    float ed_h = (lane < H) ? ed[(size_t)n * H + lane] : 0.f;

    float acc[VPL] = {};
    float den_h = 0.f;
    for (int j = j0; j < j1; ++j) {
        int s = esrc[j];
        float pm = 0.f;
        if (lane < H) {
            float v = es[(size_t)s * H + lane] + ed_h;
            v = (v > 0.f) ? v : 0.2f * v;
            pm = expf(v);
            den_h += pm;
        }
        float a = __shfl(pm, hd);
        const __half* row = hsrc + (size_t)s * HC + VPL * lane;
        if constexpr (VPL == 8) {
            uint4 raw = *(const uint4*)row;
            const __half* hv = (const __half*)&raw;
#pragma unroll
            for (int k = 0; k < 8; ++k) acc[k] += a * __half2float(hv[k]);
        } else {
            __half2 raw = *(const __half2*)row;
            acc[0] += a * __low2float(raw);
            acc[1] += a * __high2float(raw);
        }
    }

    float dv = __shfl(den_h, hd) + 1e-16f;
#pragma unroll
    for (int k = 0; k < VPL; ++k) acc[k] /= dv;
#pragma unroll
    for (int o = LPH; o < 64; o <<= 1)
#pragma unroll
        for (int k = 0; k < VPL; ++k) acc[k] += __shfl_xor(acc[k], o);

    if (lane < C / VPL) {
        int cbase = VPL * lane;
        float r[VPL];
#pragma unroll
        for (int k = 0; k < VPL; ++k) {
            float o2 = acc[k] * (1.0f / H) + bias[cbase + k];
            if (RELU) o2 = fmaxf(o2, 0.f);
            r[k] = o2;
        }
        OUT* dst = out + (size_t)n * C + cbase;
        if constexpr (VPL == 8) {
            if constexpr (sizeof(OUT) == 2) {
                __half2 h0 = __floats2half2_rn(r[0], r[1]);
                __half2 h1 = __floats2half2_rn(r[2], r[3]);
                __half2 h2 = __floats2half2_rn(r[4], r[5]);
                __half2 h3 = __floats2half2_rn(r[6], r[7]);
                uint4 pk;
                pk.x = *(unsigned*)&h0; pk.y = *(unsigned*)&h1;
                pk.z = *(unsigned*)&h2; pk.w = *(unsigned*)&h3;
                *(uint4*)dst = pk;
            } else {
                *(float4*)((float*)dst) = make_float4(r[0], r[1], r[2], r[3]);
                *(float4*)((float*)dst + 4) = make_float4(r[4], r[5], r[6], r[7]);
            }
        } else {
            *(float2*)((float*)dst) = make_float2(r[0], r[1]);
        }
    }
}

// -------- single-pass z-gather (pre-projection, for dec1) --------------------
template <int K, int H>
__global__ __launch_bounds__(256) void gat_gather_z(const __half* __restrict__ A,
                                                    const float* __restrict__ es,
                                                    const float* __restrict__ ed,
                                                    const int* __restrict__ off,
                                                    const int* __restrict__ esrc,
                                                    __half* __restrict__ z, int N) {
    constexpr int VPL = K / 64;
    int n = (blockIdx.x * blockDim.x + threadIdx.x) >> 6;
    int lane = threadIdx.x & 63;
    if (n >= N) return;
    int j0 = off[n], j1 = off[n + 1];

    float ed_h = (lane < H) ? ed[(size_t)n * H + lane] : 0.f;

    float acc[H][VPL];
#pragma unroll
    for (int h = 0; h < H; ++h)
#pragma unroll
        for (int v = 0; v < VPL; ++v) acc[h][v] = 0.f;
    float den_h = 0.f;
    for (int j = j0; j < j1; ++j) {
        int s = esrc[j];
        float pm = 0.f;
        if (lane < H) {
            float v = es[(size_t)s * H + lane] + ed_h;
            v = (v > 0.f) ? v : 0.2f * v;
            pm = expf(v);
            den_h += pm;
        }
        float a[VPL];
        const __half* row = A + (size_t)s * K + lane * VPL;
        if constexpr (VPL == 2) {
            __half2 r = *(const __half2*)row;
            a[0] = __low2float(r);
            a[1] = __high2float(r);
        } else {
            a[0] = __half2float(row[0]);
        }
#pragma unroll
        for (int h = 0; h < H; ++h) {
            float al = __shfl(pm, h);
#pragma unroll
            for (int v = 0; v < VPL; ++v) acc[h][v] += al * a[v];
        }
    }

#pragma unroll
    for (int h = 0; h < H; ++h) {
        float inv = 1.f / ((__shfl(den_h, h) + 1e-16f) * H);
        __half* dst = z + (size_t)n * (H * K) + h * K + lane * VPL;
        if constexpr (VPL == 2) {
            *(__half2*)dst = __floats2half2_rn(acc[h][0] * inv, acc[h][1] * inv);
        } else {
            dst[0] = __float2half(acc[h][0] * inv);
        }
    }
}

// ---------------- K-tiled MFMA GEMM with bias/relu (z-path) ------------------
template <int KK, typename OUTT, bool RELU>
__global__ __launch_bounds__(256) void gemm_kt(const __half* __restrict__ A,
                                               const __half* __restrict__ BT,
                                               const float* __restrict__ bias,
                                               OUTT* __restrict__ C,
                                               int M, int Nout) {
    __shared__ __align__(16) __half As[64 * 72];
    __shared__ __align__(16) __half Bs[64 * 72];
    int tid = threadIdx.x;
    int bm = blockIdx.y * 64, bn = blockIdx.x * 64;
    int wv = tid >> 6, l = tid & 63, lr = l & 15, g = l >> 4;
    float4v acc[4] = {{0.f, 0.f, 0.f, 0.f}, {0.f, 0.f, 0.f, 0.f},
                      {0.f, 0.f, 0.f, 0.f}, {0.f, 0.f, 0.f, 0.f}};
    for (int kc = 0; kc < KK; kc += 64) {
        __syncthreads();
        for (int idx = tid; idx < 512; idx += 256) {
            int row = idx >> 3, ko = (idx & 7) * 8;
            uint4 v = make_uint4(0u, 0u, 0u, 0u);
            int gr = bm + row;
            if (gr < M) v = *(const uint4*)(A + (size_t)gr * KK + kc + ko);
            *(uint4*)(&As[row * 72 + ko]) = v;
            uint4 wvv = *(const uint4*)(BT + (size_t)(bn + row) * KK + kc + ko);
            *(uint4*)(&Bs[row * 72 + ko]) = wvv;
        }
        __syncthreads();
#pragma unroll
        for (int k0 = 0; k0 < 64; k0 += 32) {
            half8v af = *reinterpret_cast<const half8v*>(&As[(16 * wv + lr) * 72 + k0 + 8 * g]);
#pragma unroll
            for (int nt = 0; nt < 4; ++nt) {
                half8v bf = *reinterpret_cast<const half8v*>(&Bs[(nt * 16 + lr) * 72 + k0 + 8 * g]);
                acc[nt] = __builtin_amdgcn_mfma_f32_16x16x32_f16(af, bf, acc[nt], 0, 0, 0);
            }
        }
    }
#pragma unroll
    for (int nt = 0; nt < 4; ++nt) {
        float b = bias[bn + nt * 16 + lr];
#pragma unroll
        for (int r = 0; r < 4; ++r) {
            int grow = bm + 16 * wv + 4 * g + r;
            if (grow < M) {
                float c = acc[nt][r] + b;
                if (RELU) c = fmaxf(c, 0.f);
                if constexpr (sizeof(OUTT) == 2)
                    C[(size_t)grow * Nout + bn + nt * 16 + lr] = __float2half(c);
                else
                    C[(size_t)grow * Nout + bn + nt * 16 + lr] = c;
            }
        }
    }
}

// ------- dec0 gather: 16-row table, scores via batch lookup, single-pass -----
__global__ __launch_bounds__(256) void gat_gather_d0(const float* __restrict__ hsrc,
                                                     const float* __restrict__ es16,
                                                     const float* __restrict__ ed16,
                                                     const int* __restrict__ off,
                                                     const int* __restrict__ esrc,
                                                     const int* __restrict__ batch,
                                                     const float* __restrict__ bias,
                                                     __half* __restrict__ out, int N) {
    int n = (blockIdx.x * blockDim.x + threadIdx.x) >> 6;
    int lane = threadIdx.x & 63;
    if (n >= N) return;
    int j0 = off[n], j1 = off[n + 1];
    float ed_v = ed16[batch[n]];
    float acc = 0.f, den = 0.f;
    for (int j = j0; j < j1; ++j) {
        int s = esrc[j];
        int g = batch[s];
        float v = es16[g] + ed_v;
        v = (v > 0.f) ? v : 0.2f * v;
        float pm = expf(v);
        den += pm;
        acc += pm * hsrc[(size_t)g * 64 + lane];
    }
    float o = acc / (den + 1e-16f) + bias[lane];
    o = fmaxf(o, 0.f);
    out[(size_t)n * 64 + lane] = __float2half(o);
}

// ---------------- pooling ----------------
__global__ __launch_bounds__(256) void gate_kernel(const __half* __restrict__ h,
                                                   const float* __restrict__ w1,
                                                   const float* __restrict__ b1,
                                                   const float* __restrict__ w2,
                                                   const float* __restrict__ b2,
                                                   float* __restrict__ gate, int N) {
    int n = (blockIdx.x * blockDim.x + threadIdx.x) >> 6;
    int lane = threadIdx.x & 63;
    if (n >= N) return;
    float hv = __half2float(h[(size_t)n * 64 + lane]);
    float t = b1[lane];
    for (int c = 0; c < 64; ++c) t += __shfl(hv, c) * w1[c * 64 + lane];
    t = fmaxf(t, 0.f);
    float g = t * w2[lane];
#pragma unroll
    for (int o = 32; o; o >>= 1) g += __shfl_xor(g, o);
    g += b2[0];
    if (lane == 0) gate[n] = g;
}

__global__ __launch_bounds__(256) void gmax_kernel(const float* __restrict__ gate,
                                                   const int* __restrict__ batch,
                                                   unsigned* __restrict__ gm, int N) {
    __shared__ unsigned smax[16];
    int t = threadIdx.x;
    if (t < 16) smax[t] = 0u;
    __syncthreads();
    for (int i = blockIdx.x * blockDim.x + t; i < N; i += gridDim.x * blockDim.x)
        atomicMax(&smax[batch[i]], f2o(gate[i]));
    __syncthreads();
    if (t < 16 && smax[t]) atomicMax(&gm[t], smax[t]);
}

__global__ __launch_bounds__(256) void pool_p(const float* __restrict__ gate,
                                              const unsigned* __restrict__ gm,
                                              const int* __restrict__ batch,
                                              float* __restrict__ pg,
                                              float* __restrict__ gden, int N) {
    __shared__ float part[16];
    int t = threadIdx.x;
    if (t < 16) part[t] = 0.f;
    __syncthreads();
    int n = blockIdx.x * blockDim.x + t;
    if (n < N) {
        int b = batch[n];
        unsigned u = gm[b];
        float mf = u ? o2f(u) : 0.f;
        float p = expf(gate[n] - mf);
        pg[n] = p;
        atomicAdd(&part[b], p);
    }
    __syncthreads();
    if (t < 16 && part[t] != 0.f) atomicAdd(&gden[t], part[t]);
}

#define NODES_PER_WAVE 128
__global__ __launch_bounds__(256) void pool_sum(const __half* __restrict__ h,
                                                const float* __restrict__ pg,
                                                const int* __restrict__ batch,
                                                float* __restrict__ pooled, int N) {
    int w = (blockIdx.x * blockDim.x + threadIdx.x) >> 6;
    int lane = threadIdx.x & 63;
    int start = w * NODES_PER_WAVE;
    if (start >= N) return;
    int curg = batch[start];
    float acc = 0.f;
    for (int i = 0; i < NODES_PER_WAVE; ++i) {
        int n = start + i;
        if (n >= N) break;
        int g = batch[n];
        if (g != curg) {
            atomicAdd(&pooled[curg * 64 + lane], acc);
            acc = 0.f;
            curg = g;
        }
        acc += pg[n] * __half2float(h[(size_t)n * 64 + lane]);
    }
    atomicAdd(&pooled[curg * 64 + lane], acc);
}

__global__ void dec_prep(const float* __restrict__ pooled, const float* __restrict__ gden,
                         const float* __restrict__ Wd0, const float* __restrict__ asd,
                         const float* __restrict__ add, float* __restrict__ hd016,
                         float* __restrict__ es16, float* __restrict__ ed16) {
    int g = blockIdx.x;
    int lane = threadIdx.x;
    float pn = pooled[g * 64 + lane] / (gden[g] + 1e-16f);
    float o = 0.f;
    for (int c = 0; c < 64; ++c) o += __shfl(pn, c) * Wd0[c * 64 + lane];
    hd016[g * 64 + lane] = o;
    float s = o * asd[lane], d = o * add[lane];
#pragma unroll
    for (int off = 32; off; off >>= 1) {
        s += __shfl_xor(s, off);
        d += __shfl_xor(d, off);
    }
    if (lane == 0) {
        es16[g] = s;
        ed16[g] = d;
    }
}

// ---------------- host ----------------
static inline int cdiv(int a, int b) { return (a + b - 1) / b; }

extern "C" void kernel_launch(void* const* d_in, const int* in_sizes, int n_in,
                              void* d_out, int out_size, void* d_ws, size_t ws_size,
                              hipStream_t stream) {
    const float* x      = (const float*)d_in[0];
    const int*   ei     = (const int*)  d_in[1];
    const int*   batch  = (const int*)  d_in[2];
    const float* W_e0   = (const float*)d_in[3];
    const float* a_s_e0 = (const float*)d_in[4];
    const float* a_d_e0 = (const float*)d_in[5];
    const float* b_e0   = (const float*)d_in[6];
    const float* W_e1   = (const float*)d_in[7];
    const float* a_s_e1 = (const float*)d_in[8];
    const float* a_d_e1 = (const float*)d_in[9];
    const float* b_e1   = (const float*)d_in[10];
    const float* W_d0   = (const float*)d_in[11];
    const float* a_s_d0 = (const float*)d_in[12];
    const float* a_d_d0 = (const float*)d_in[13];
    const float* b_d0   = (const float*)d_in[14];
    const float* W_d1   = (const float*)d_in[15];
    const float* a_s_d1 = (const float*)d_in[16];
    const float* a_d_d1 = (const float*)d_in[17];
    const float* b_d1   = (const float*)d_in[18];
    const float* g_w1   = (const float*)d_in[19];
    const float* g_b1   = (const float*)d_in[20];
    const float* g_w2   = (const float*)d_in[21];
    const float* g_b2   = (const float*)d_in[22];

    const int N    = in_sizes[2];
    const int E    = in_sizes[1] / 2;
    const int Etot = E + N;
    const int Din  = in_sizes[0] / N;  // 128

    char* w = (char*)d_ws;
    size_t o = 0;
    auto alloc = [&](size_t bytes) -> void* {
        void* p = w + o;
        o = (o + bytes + 255) & ~(size_t)255;
        return p;
    };
    __half*   h16    = (__half*)  alloc((size_t)N * 512 * 2);  // also z (dec1)
    __half*   x16    = (__half*)  alloc((size_t)N * Din * 2);
    __half*   bufA   = (__half*)  alloc((size_t)N * 64 * 2);
    __half*   bufB   = (__half*)  alloc((size_t)N * 64 * 2);
    __half*   wt_e0  = (__half*)  alloc((size_t)512 * 128 * 2);
    __half*   wt_e1  = (__half*)  alloc((size_t)512 * 64 * 2);
    __half*   wst_d1 = (__half*)  alloc((size_t)128 * 64 * 2);
    float*    ws_e0  = (float*)   alloc(8 * 128 * 4);
    float*    wd_e0  = (float*)   alloc(8 * 128 * 4);
    float*    ws_e1  = (float*)   alloc(8 * 64 * 4);
    float*    wd_e1  = (float*)   alloc(8 * 64 * 4);
    float*    ws_d1  = (float*)   alloc(64 * 4);
    float*    wd_d1  = (float*)   alloc(64 * 4);
    float*    es     = (float*)   alloc((size_t)N * 8 * 4);
    float*    ed     = (float*)   alloc((size_t)N * 8 * 4);
    float*    gate   = (float*)   alloc((size_t)N * 4);
    float*    pg     = (float*)   alloc((size_t)N * 4);
    int*      off    = (int*)     alloc((size_t)(N + 1) * 4);
    int*      cnt    = (int*)     alloc((size_t)N * 4);
    int*      esrc   = (int*)     alloc((size_t)Etot * 4);
    int*      bsum   = (int*)     alloc(256 * 4);
    unsigned* gm     = (unsigned*)alloc(16 * 4);
    float*    gden   = (float*)   alloc(16 * 4);
    float*    pooled = (float*)   alloc(16 * 64 * 4);
    float*    hd016  = (float*)   alloc(16 * 64 * 4);
    float*    es16   = (float*)   alloc(16 * 4);
    float*    ed16   = (float*)   alloc(16 * 4);
    (void)ws_size; (void)n_in; (void)out_size;

    const int nodeWaveGrid = cdiv(N, 4);
    const int edgeGrid     = cdiv(Etot, TB);
    const int scanBlocks   = cdiv(N, 256);

    // ---- CSR ----
    hipMemsetAsync(cnt, 0, (size_t)N * 4, stream);
    csr_count<<<edgeGrid, TB, 0, stream>>>(ei, E, Etot, cnt);
    scan_phase1<<<scanBlocks, 256, 0, stream>>>(cnt, esrc /*temp incl*/, bsum, N);
    scan_phase2<<<1, 256, 0, stream>>>(bsum, scanBlocks);
    scan_phase3<<<scanBlocks, 256, 0, stream>>>(esrc, bsum, off, N);
    hipMemsetAsync(cnt, 0, (size_t)N * 4, stream);
    csr_fill<<<edgeGrid, TB, 0, stream>>>(ei, E, Etot, off, cnt, esrc);

    // ---- prep ----
    cast_f2h<<<cdiv(N * Din / 2, TB), TB, 0, stream>>>(x, x16, N * Din);
    transpose_cast<<<cdiv(512 * 128, TB), TB, 0, stream>>>(W_e0, wt_e0, Din, 512);
    transpose_cast<<<cdiv(512 * 64, TB), TB, 0, stream>>>(W_e1, wt_e1, 64, 512);
    make_wstackT<<<cdiv(128 * 64, TB), TB, 0, stream>>>(W_d1, wst_d1, 64, 1, 128);
    make_ws<<<cdiv(8 * 128, TB), TB, 0, stream>>>(W_e0, a_s_e0, a_d_e0, ws_e0, wd_e0, 128, 8, 64);
    make_ws<<<cdiv(8 * 64, TB), TB, 0, stream>>>(W_e1, a_s_e1, a_d_e1, ws_e1, wd_e1, 64, 8, 64);
    make_ws<<<1, TB, 0, stream>>>(W_d1, a_s_d1, a_d_d1, ws_d1, wd_d1, 64, 1, 128);

    // ---- encoder layer 0 (H=8, relu): post-projection ----
    scores_from_A<128, 8><<<nodeWaveGrid, TB, 0, stream>>>(x16, ws_e0, wd_e0, es, ed, N);
    {
        dim3 grid(512 / 64, cdiv(N, 64));
        gemm_mfma<128><<<grid, TB, 0, stream>>>(x16, wt_e0, h16, N, 512);
    }
    gat_gather_h<8, 64, true, __half><<<nodeWaveGrid, TB, 0, stream>>>(
        h16, es, ed, off, esrc, b_e0, bufA, N);

    // ---- encoder layer 1 (H=8, no relu): post-projection ----
    scores_from_A<64, 8><<<nodeWaveGrid, TB, 0, stream>>>(bufA, ws_e1, wd_e1, es, ed, N);
    {
        dim3 grid(512 / 64, cdiv(N, 64));
        gemm_mfma<64><<<grid, TB, 0, stream>>>(bufA, wt_e1, h16, N, 512);
    }
    gat_gather_h<8, 64, false, __half><<<nodeWaveGrid, TB, 0, stream>>>(
        h16, es, ed, off, esrc, b_e1, bufB, N);

    // ---- pooling ----
    hipMemsetAsync(gm, 0, 16 * 4, stream);
    hipMemsetAsync(gden, 0, 16 * 4, stream);
    hipMemsetAsync(pooled, 0, 16 * 64 * 4, stream);
    gate_kernel<<<nodeWaveGrid, TB, 0, stream>>>(bufB, g_w1, g_b1, g_w2, g_b2, gate, N);
    gmax_kernel<<<256, TB, 0, stream>>>(gate, batch, gm, N);
    pool_p<<<cdiv(N, TB), TB, 0, stream>>>(gate, gm, batch, pg, gden, N);
    pool_sum<<<cdiv(cdiv(N, NODES_PER_WAVE), 4), TB, 0, stream>>>(bufB, pg, batch, pooled, N);
    dec_prep<<<16, 64, 0, stream>>>(pooled, gden, W_d0, a_s_d0, a_d_d0, hd016, es16, ed16);

    // ---- decoder layer 0 (H=1, relu): 16-row table, scores inline ----
    gat_gather_d0<<<nodeWaveGrid, TB, 0, stream>>>(
        hd016, es16, ed16, off, esrc, batch, b_d0, bufA, N);

    // ---- decoder layer 1 (H=1, C=128, no relu): z-path -> d_out ----
    scores_from_A<64, 1><<<nodeWaveGrid, TB, 0, stream>>>(bufA, ws_d1, wd_d1, es, ed, N);
    gat_gather_z<64, 1><<<nodeWaveGrid, TB, 0, stream>>>(bufA, es, ed, off, esrc, h16 /*z*/, N);
    {
        dim3 grid(2, cdiv(N, 64));
        gemm_kt<64, float, false><<<grid, TB, 0, stream>>>(h16 /*z*/, wst_d1, b_d1, (float*)d_out, N, 128);
    }
}

// Round 8
// 534.181 us; speedup vs baseline: 1.2361x; 1.0981x over previous
//
#include <hip/hip_runtime.h>
#include <hip/hip_fp16.h>
#include <math.h>

#define TB 256

typedef _Float16 half8v __attribute__((ext_vector_type(8)));
typedef float float4v __attribute__((ext_vector_type(4)));

static __device__ __forceinline__ unsigned f2o(float x) {
    unsigned b = __float_as_uint(x);
    return (b & 0x80000000u) ? ~b : (b | 0x80000000u);
}
static __device__ __forceinline__ float o2f(unsigned u) {
    return (u & 0x80000000u) ? __uint_as_float(u & 0x7FFFFFFFu) : __uint_as_float(~u);
}

static __device__ __forceinline__ int edge_src(const int* ei, int E, int e) {
    return (e < E) ? ei[e] : (e - E);
}
static __device__ __forceinline__ int edge_dst(const int* ei, int E, int e) {
    return (e < E) ? ei[E + e] : (e - E);
}

// ---------------- CSR build ----------------
__global__ void csr_count(const int* __restrict__ ei, int E, int Etot, int* __restrict__ cnt) {
    int e = blockIdx.x * blockDim.x + threadIdx.x;
    if (e >= Etot) return;
    atomicAdd(&cnt[edge_dst(ei, E, e)], 1);
}

__global__ __launch_bounds__(256) void scan_phase1(const int* __restrict__ cnt,
                                                   int* __restrict__ incl,
                                                   int* __restrict__ bsum, int n) {
    __shared__ int sdata[256];
    int t = threadIdx.x;
    int base = blockIdx.x * 256;
    int v = (base + t < n) ? cnt[base + t] : 0;
    for (int d = 1; d < 256; d <<= 1) {
        sdata[t] = v; __syncthreads();
        if (t >= d) v += sdata[t - d];
        __syncthreads();
    }
    if (base + t < n) incl[base + t] = v;
    if (t == 255) bsum[blockIdx.x] = v;
}

__global__ void scan_phase2(int* bsum, int nb) {
    __shared__ int sdata[256];
    int t = threadIdx.x;
    int v = (t < nb) ? bsum[t] : 0;
    for (int d = 1; d < 256; d <<= 1) {
        sdata[t] = v; __syncthreads();
        if (t >= d) v += sdata[t - d];
        __syncthreads();
    }
    if (t < nb) bsum[t] = v;
}

__global__ __launch_bounds__(256) void scan_phase3(const int* __restrict__ incl,
                                                   const int* __restrict__ bsum,
                                                   int* __restrict__ off, int n) {
    int i = blockIdx.x * 256 + threadIdx.x;
    if (i < n) off[i + 1] = incl[i] + (blockIdx.x ? bsum[blockIdx.x - 1] : 0);
    if (i == 0) off[0] = 0;
}

__global__ void csr_fill(const int* __restrict__ ei, int E, int Etot,
                         const int* __restrict__ off, int* __restrict__ cur,
                         int* __restrict__ esrc) {
    int e = blockIdx.x * blockDim.x + threadIdx.x;
    if (e >= Etot) return;
    int d = edge_dst(ei, E, e);
    int pos = atomicAdd(&cur[d], 1);
    esrc[off[d] + pos] = edge_src(ei, E, e);
}

// graph range table from sorted batch: gstart[g] = first node of graph g
__global__ void find_gstart(const int* __restrict__ batch, int* __restrict__ gstart, int N) {
    int n = blockIdx.x * blockDim.x + threadIdx.x;
    if (n >= N) return;
    int b = batch[n];
    int prev = n ? batch[n - 1] : -1;
    for (int g = prev + 1; g <= b; ++g) gstart[g] = n;
    if (n == N - 1)
        for (int g = b + 1; g <= 16; ++g) gstart[g] = N;
}

// ---------------- prep ----------------
__global__ void cast_f2h(const float* __restrict__ in, __half* __restrict__ out, int n) {
    int i2 = (blockIdx.x * blockDim.x + threadIdx.x) * 2;
    if (i2 + 1 < n) {
        float2 v = *(const float2*)(in + i2);
        *(__half2*)(out + i2) = __floats2half2_rn(v.x, v.y);
    } else if (i2 < n) {
        out[i2] = __float2half(in[i2]);
    }
}

__global__ void make_ws(const float* __restrict__ W, const float* __restrict__ a_s,
                        const float* __restrict__ a_d, float* __restrict__ ws,
                        float* __restrict__ wd, int K, int H, int C) {
    int i = blockIdx.x * blockDim.x + threadIdx.x;
    if (i >= H * K) return;
    int h = i / K, k = i % K;
    const float* wrow = W + (size_t)k * H * C + h * C;
    float s = 0.f, d = 0.f;
    for (int c = 0; c < C; ++c) {
        s += wrow[c] * a_s[h * C + c];
        d += wrow[c] * a_d[h * C + c];
    }
    ws[i] = s;
    wd[i] = d;
}

__global__ void transpose_cast(const float* __restrict__ W, __half* __restrict__ WT,
                               int K, int N) {
    int i = blockIdx.x * blockDim.x + threadIdx.x;
    if (i >= N * K) return;
    int nn = i / K, kk = i % K;
    WT[i] = __float2half(W[kk * N + nn]);
}

__global__ void make_wstackT(const float* __restrict__ W, __half* __restrict__ WT,
                             int K, int H, int C) {
    int i = blockIdx.x * blockDim.x + threadIdx.x;
    if (i >= K * H * C) return;
    int c = i / (H * K);
    int rem = i % (H * K);
    int h = rem / K, k = rem % K;
    WT[i] = __float2half(W[(size_t)k * H * C + h * C + c]);
}

// ---------------- MFMA GEMM (post-projection) ----------------
template <int K>
__global__ __launch_bounds__(256) void gemm_mfma(const __half* __restrict__ A,
                                                 const __half* __restrict__ BT,
                                                 __half* __restrict__ C,
                                                 int M, int N) {
    constexpr int KP = K + 8;
    __shared__ __align__(16) __half As[64 * KP];
    __shared__ __align__(16) __half Bs[64 * KP];
    int tid = threadIdx.x;
    int bm = blockIdx.y * 64, bn = blockIdx.x * 64;
    constexpr int LPR = K / 8;
    for (int idx = tid; idx < 64 * LPR; idx += 256) {
        int row = idx / LPR, koff = (idx % LPR) * 8;
        uint4 v = make_uint4(0u, 0u, 0u, 0u);
        int gr = bm + row;
        if (gr < M) v = *(const uint4*)(A + (size_t)gr * K + koff);
        *(uint4*)(&As[row * KP + koff]) = v;
        uint4 wv = *(const uint4*)(BT + (size_t)(bn + row) * K + koff);
        *(uint4*)(&Bs[row * KP + koff]) = wv;
    }
    __syncthreads();
    int wv_ = tid >> 6, l = tid & 63;
    int lr = l & 15, g = l >> 4;
    float4v acc[4] = {{0.f, 0.f, 0.f, 0.f}, {0.f, 0.f, 0.f, 0.f},
                      {0.f, 0.f, 0.f, 0.f}, {0.f, 0.f, 0.f, 0.f}};
    const __half* ap = &As[(16 * wv_ + lr) * KP + 8 * g];
    const __half* bp = &Bs[lr * KP + 8 * g];
#pragma unroll
    for (int k0 = 0; k0 < K; k0 += 32) {
        half8v af = *reinterpret_cast<const half8v*>(ap + k0);
#pragma unroll
        for (int nt = 0; nt < 4; ++nt) {
            half8v bf = *reinterpret_cast<const half8v*>(bp + nt * 16 * KP + k0);
            acc[nt] = __builtin_amdgcn_mfma_f32_16x16x32_f16(af, bf, acc[nt], 0, 0, 0);
        }
    }
#pragma unroll
    for (int nt = 0; nt < 4; ++nt) {
#pragma unroll
        for (int r = 0; r < 4; ++r) {
            int grow = bm + 16 * wv_ + 4 * g + r;
            if (grow < M)
                C[(size_t)grow * N + bn + nt * 16 + lr] = __float2half(acc[nt][r]);
        }
    }
}

// ---------------- scores directly from A ----------------
template <int K, int H>
__global__ __launch_bounds__(256) void scores_from_A(const __half* __restrict__ A,
                                                     const float* __restrict__ ws,
                                                     const float* __restrict__ wd,
                                                     float* __restrict__ es,
                                                     float* __restrict__ ed, int N) {
    constexpr int VPL = K / 64;
    int n = (blockIdx.x * blockDim.x + threadIdx.x) >> 6;
    int lane = threadIdx.x & 63;
    if (n >= N) return;
    float a[VPL];
    const __half* row = A + (size_t)n * K + lane * VPL;
    if constexpr (VPL == 2) {
        __half2 r = *(const __half2*)row;
        a[0] = __low2float(r);
        a[1] = __high2float(r);
    } else {
        a[0] = __half2float(row[0]);
    }
    float s[H], d[H];
#pragma unroll
    for (int h = 0; h < H; ++h) {
        s[h] = 0.f; d[h] = 0.f;
#pragma unroll
        for (int v = 0; v < VPL; ++v) {
            s[h] += a[v] * ws[h * K + lane * VPL + v];
            d[h] += a[v] * wd[h * K + lane * VPL + v];
        }
    }
#pragma unroll
    for (int o = 1; o < 64; o <<= 1) {
#pragma unroll
        for (int h = 0; h < H; ++h) {
            s[h] += __shfl_xor(s[h], o);
            d[h] += __shfl_xor(d[h], o);
        }
    }
    if (lane == 0) {
#pragma unroll
        for (int h = 0; h < H; ++h) {
            es[(size_t)n * H + h] = s[h];
            ed[(size_t)n * H + h] = d[h];
        }
    }
}

// ------- FUSED single-pass softmax + aggregation from fp16 h ----
template <int H, int C, bool RELU, typename OUT>
__global__ __launch_bounds__(256) void gat_gather_h(const __half* __restrict__ hsrc,
                                                    const float* __restrict__ es,
                                                    const float* __restrict__ ed,
                                                    const int* __restrict__ off,
                                                    const int* __restrict__ esrc,
                                                    const float* __restrict__ bias,
                                                    OUT* __restrict__ out, int N) {
    constexpr int HC = H * C;
    constexpr int VPL = HC / 64;
    constexpr int LPH = 64 / H;
    int n = (blockIdx.x * blockDim.x + threadIdx.x) >> 6;
    int lane = threadIdx.x & 63;
    if (n >= N) return;
    int hd = lane / LPH;
    int j0 = off[n], j1 = off[n + 1];

    float ed_h = (lane < H) ? ed[(size_t)n * H + lane] : 0.f;

    float acc[VPL] = {};
    float den_h = 0.f;
    for (int j = j0; j < j1; ++j) {
        int s = esrc[j];
        float pm = 0.f;
        if (lane < H) {
            float v = es[(size_t)s * H + lane] + ed_h;
            v = (v > 0.f) ? v : 0.2f * v;
            pm = expf(v);
            den_h += pm;
        }
        float a = __shfl(pm, hd);
        const __half* row = hsrc + (size_t)s * HC + VPL * lane;
        if constexpr (VPL == 8) {
            uint4 raw = *(const uint4*)row;
            const __half* hv = (const __half*)&raw;
#pragma unroll
            for (int k = 0; k < 8; ++k) acc[k] += a * __half2float(hv[k]);
        } else {
            __half2 raw = *(const __half2*)row;
            acc[0] += a * __low2float(raw);
            acc[1] += a * __high2float(raw);
        }
    }

    float dv = __shfl(den_h, hd) + 1e-16f;
#pragma unroll
    for (int k = 0; k < VPL; ++k) acc[k] /= dv;
#pragma unroll
    for (int o = LPH; o < 64; o <<= 1)
#pragma unroll
        for (int k = 0; k < VPL; ++k) acc[k] += __shfl_xor(acc[k], o);

    if (lane < C / VPL) {
        int cbase = VPL * lane;
        float r[VPL];
#pragma unroll
        for (int k = 0; k < VPL; ++k) {
            float o2 = acc[k] * (1.0f / H) + bias[cbase + k];
            if (RELU) o2 = fmaxf(o2, 0.f);
            r[k] = o2;
        }
        OUT* dst = out + (size_t)n * C + cbase;
        if constexpr (VPL == 8) {
            if constexpr (sizeof(OUT) == 2) {
                __half2 h0 = __floats2half2_rn(r[0], r[1]);
                __half2 h1 = __floats2half2_rn(r[2], r[3]);
                __half2 h2 = __floats2half2_rn(r[4], r[5]);
                __half2 h3 = __floats2half2_rn(r[6], r[7]);
                uint4 pk;
                pk.x = *(unsigned*)&h0; pk.y = *(unsigned*)&h1;
                pk.z = *(unsigned*)&h2; pk.w = *(unsigned*)&h3;
                *(uint4*)dst = pk;
            } else {
                *(float4*)((float*)dst) = make_float4(r[0], r[1], r[2], r[3]);
                *(float4*)((float*)dst + 4) = make_float4(r[4], r[5], r[6], r[7]);
            }
        } else {
            *(float2*)((float*)dst) = make_float2(r[0], r[1]);
        }
    }
}

// -------- single-pass z-gather (pre-projection, dec1) ----------------
template <int K, int H>
__global__ __launch_bounds__(256) void gat_gather_z(const __half* __restrict__ A,
                                                    const float* __restrict__ es,
                                                    const float* __restrict__ ed,
                                                    const int* __restrict__ off,
                                                    const int* __restrict__ esrc,
                                                    __half* __restrict__ z, int N) {
    constexpr int VPL = K / 64;
    int n = (blockIdx.x * blockDim.x + threadIdx.x) >> 6;
    int lane = threadIdx.x & 63;
    if (n >= N) return;
    int j0 = off[n], j1 = off[n + 1];

    float ed_h = (lane < H) ? ed[(size_t)n * H + lane] : 0.f;

    float acc[H][VPL];
#pragma unroll
    for (int h = 0; h < H; ++h)
#pragma unroll
        for (int v = 0; v < VPL; ++v) acc[h][v] = 0.f;
    float den_h = 0.f;
    for (int j = j0; j < j1; ++j) {
        int s = esrc[j];
        float pm = 0.f;
        if (lane < H) {
            float v = es[(size_t)s * H + lane] + ed_h;
            v = (v > 0.f) ? v : 0.2f * v;
            pm = expf(v);
            den_h += pm;
        }
        float a[VPL];
        const __half* row = A + (size_t)s * K + lane * VPL;
        if constexpr (VPL == 2) {
            __half2 r = *(const __half2*)row;
            a[0] = __low2float(r);
            a[1] = __high2float(r);
        } else {
            a[0] = __half2float(row[0]);
        }
#pragma unroll
        for (int h = 0; h < H; ++h) {
            float al = __shfl(pm, h);
#pragma unroll
            for (int v = 0; v < VPL; ++v) acc[h][v] += al * a[v];
        }
    }

#pragma unroll
    for (int h = 0; h < H; ++h) {
        float inv = 1.f / ((__shfl(den_h, h) + 1e-16f) * H);
        __half* dst = z + (size_t)n * (H * K) + h * K + lane * VPL;
        if constexpr (VPL == 2) {
            *(__half2*)dst = __floats2half2_rn(acc[h][0] * inv, acc[h][1] * inv);
        } else {
            dst[0] = __float2half(acc[h][0] * inv);
        }
    }
}

// ---------------- K-tiled MFMA GEMM with bias/relu (z-path) ------------------
template <int KK, typename OUTT, bool RELU>
__global__ __launch_bounds__(256) void gemm_kt(const __half* __restrict__ A,
                                               const __half* __restrict__ BT,
                                               const float* __restrict__ bias,
                                               OUTT* __restrict__ C,
                                               int M, int Nout) {
    __shared__ __align__(16) __half As[64 * 72];
    __shared__ __align__(16) __half Bs[64 * 72];
    int tid = threadIdx.x;
    int bm = blockIdx.y * 64, bn = blockIdx.x * 64;
    int wv = tid >> 6, l = tid & 63, lr = l & 15, g = l >> 4;
    float4v acc[4] = {{0.f, 0.f, 0.f, 0.f}, {0.f, 0.f, 0.f, 0.f},
                      {0.f, 0.f, 0.f, 0.f}, {0.f, 0.f, 0.f, 0.f}};
    for (int kc = 0; kc < KK; kc += 64) {
        __syncthreads();
        for (int idx = tid; idx < 512; idx += 256) {
            int row = idx >> 3, ko = (idx & 7) * 8;
            uint4 v = make_uint4(0u, 0u, 0u, 0u);
            int gr = bm + row;
            if (gr < M) v = *(const uint4*)(A + (size_t)gr * KK + kc + ko);
            *(uint4*)(&As[row * 72 + ko]) = v;
            uint4 wvv = *(const uint4*)(BT + (size_t)(bn + row) * KK + kc + ko);
            *(uint4*)(&Bs[row * 72 + ko]) = wvv;
        }
        __syncthreads();
#pragma unroll
        for (int k0 = 0; k0 < 64; k0 += 32) {
            half8v af = *reinterpret_cast<const half8v*>(&As[(16 * wv + lr) * 72 + k0 + 8 * g]);
#pragma unroll
            for (int nt = 0; nt < 4; ++nt) {
                half8v bf = *reinterpret_cast<const half8v*>(&Bs[(nt * 16 + lr) * 72 + k0 + 8 * g]);
                acc[nt] = __builtin_amdgcn_mfma_f32_16x16x32_f16(af, bf, acc[nt], 0, 0, 0);
            }
        }
    }
#pragma unroll
    for (int nt = 0; nt < 4; ++nt) {
        float b = bias[bn + nt * 16 + lr];
#pragma unroll
        for (int r = 0; r < 4; ++r) {
            int grow = bm + 16 * wv + 4 * g + r;
            if (grow < M) {
                float c = acc[nt][r] + b;
                if (RELU) c = fmaxf(c, 0.f);
                if constexpr (sizeof(OUTT) == 2)
                    C[(size_t)grow * Nout + bn + nt * 16 + lr] = __float2half(c);
                else
                    C[(size_t)grow * Nout + bn + nt * 16 + lr] = c;
            }
        }
    }
}

// ------- dec0 gather: 16-row table, scores via batch lookup ------------------
__global__ __launch_bounds__(256) void gat_gather_d0(const float* __restrict__ hsrc,
                                                     const float* __restrict__ es16,
                                                     const float* __restrict__ ed16,
                                                     const int* __restrict__ off,
                                                     const int* __restrict__ esrc,
                                                     const int* __restrict__ batch,
                                                     const float* __restrict__ bias,
                                                     __half* __restrict__ out, int N) {
    int n = (blockIdx.x * blockDim.x + threadIdx.x) >> 6;
    int lane = threadIdx.x & 63;
    if (n >= N) return;
    int j0 = off[n], j1 = off[n + 1];
    float ed_v = ed16[batch[n]];
    float acc = 0.f, den = 0.f;
    for (int j = j0; j < j1; ++j) {
        int s = esrc[j];
        int g = batch[s];
        float v = es16[g] + ed_v;
        v = (v > 0.f) ? v : 0.2f * v;
        float pm = expf(v);
        den += pm;
        acc += pm * hsrc[(size_t)g * 64 + lane];
    }
    float o = acc / (den + 1e-16f) + bias[lane];
    o = fmaxf(o, 0.f);
    out[(size_t)n * 64 + lane] = __float2half(o);
}

// ---------------- pooling ----------------
__global__ __launch_bounds__(256) void gate_kernel(const __half* __restrict__ h,
                                                   const float* __restrict__ w1,
                                                   const float* __restrict__ b1,
                                                   const float* __restrict__ w2,
                                                   const float* __restrict__ b2,
                                                   float* __restrict__ gate, int N) {
    int n = (blockIdx.x * blockDim.x + threadIdx.x) >> 6;
    int lane = threadIdx.x & 63;
    if (n >= N) return;
    float hv = __half2float(h[(size_t)n * 64 + lane]);
    float t = b1[lane];
    for (int c = 0; c < 64; ++c) t += __shfl(hv, c) * w1[c * 64 + lane];
    t = fmaxf(t, 0.f);
    float g = t * w2[lane];
#pragma unroll
    for (int o = 32; o; o >>= 1) g += __shfl_xor(g, o);
    g += b2[0];
    if (lane == 0) gate[n] = g;
}

__global__ __launch_bounds__(256) void gmax_kernel(const float* __restrict__ gate,
                                                   const int* __restrict__ batch,
                                                   unsigned* __restrict__ gm, int N) {
    __shared__ unsigned smax[16];
    int t = threadIdx.x;
    if (t < 16) smax[t] = 0u;
    __syncthreads();
    for (int i = blockIdx.x * blockDim.x + t; i < N; i += gridDim.x * blockDim.x)
        atomicMax(&smax[batch[i]], f2o(gate[i]));
    __syncthreads();
    if (t < 16 && smax[t]) atomicMax(&gm[t], smax[t]);
}

__global__ __launch_bounds__(256) void pool_p(const float* __restrict__ gate,
                                              const unsigned* __restrict__ gm,
                                              const int* __restrict__ batch,
                                              float* __restrict__ pg,
                                              float* __restrict__ gden, int N) {
    __shared__ float part[16];
    int t = threadIdx.x;
    if (t < 16) part[t] = 0.f;
    __syncthreads();
    int n = blockIdx.x * blockDim.x + t;
    if (n < N) {
        int b = batch[n];
        unsigned u = gm[b];
        float mf = u ? o2f(u) : 0.f;
        float p = expf(gate[n] - mf);
        pg[n] = p;
        atomicAdd(&part[b], p);
    }
    __syncthreads();
    if (t < 16 && part[t] != 0.f) atomicAdd(&gden[t], part[t]);
}

// parallel pooled sum: grid(16, SPLIT), 4 waves/block, register acc + LDS combine
#define POOL_SPLIT 32
__global__ __launch_bounds__(256) void pool_sum2(const __half* __restrict__ h,
                                                 const float* __restrict__ pg,
                                                 const int* __restrict__ gstart,
                                                 float* __restrict__ pooled, int N) {
    __shared__ float part[256];
    int g = blockIdx.x;
    int r0 = gstart[g], r1 = gstart[g + 1];
    int len = r1 - r0;
    int chunk = (len + POOL_SPLIT - 1) / POOL_SPLIT;
    int s0 = r0 + blockIdx.y * chunk;
    int s1 = min(s0 + chunk, r1);
    int wv = threadIdx.x >> 6, lane = threadIdx.x & 63;
    float acc = 0.f;
    for (int n = s0 + wv; n < s1; n += 4)
        acc += pg[n] * __half2float(h[(size_t)n * 64 + lane]);
    part[threadIdx.x] = acc;
    __syncthreads();
    if (threadIdx.x < 64) {
        float tot = part[threadIdx.x] + part[64 + threadIdx.x] +
                    part[128 + threadIdx.x] + part[192 + threadIdx.x];
        if (tot != 0.f) atomicAdd(&pooled[g * 64 + threadIdx.x], tot);
    }
}

__global__ void dec_prep(const float* __restrict__ pooled, const float* __restrict__ gden,
                         const float* __restrict__ Wd0, const float* __restrict__ asd,
                         const float* __restrict__ add, float* __restrict__ hd016,
                         float* __restrict__ es16, float* __restrict__ ed16) {
    int g = blockIdx.x;
    int lane = threadIdx.x;
    float pn = pooled[g * 64 + lane] / (gden[g] + 1e-16f);
    float o = 0.f;
    for (int c = 0; c < 64; ++c) o += __shfl(pn, c) * Wd0[c * 64 + lane];
    hd016[g * 64 + lane] = o;
    float s = o * asd[lane], d = o * add[lane];
#pragma unroll
    for (int off = 32; off; off >>= 1) {
        s += __shfl_xor(s, off);
        d += __shfl_xor(d, off);
    }
    if (lane == 0) {
        es16[g] = s;
        ed16[g] = d;
    }
}

// ---------------- host ----------------
static inline int cdiv(int a, int b) { return (a + b - 1) / b; }

extern "C" void kernel_launch(void* const* d_in, const int* in_sizes, int n_in,
                              void* d_out, int out_size, void* d_ws, size_t ws_size,
                              hipStream_t stream) {
    const float* x      = (const float*)d_in[0];
    const int*   ei     = (const int*)  d_in[1];
    const int*   batch  = (const int*)  d_in[2];
    const float* W_e0   = (const float*)d_in[3];
    const float* a_s_e0 = (const float*)d_in[4];
    const float* a_d_e0 = (const float*)d_in[5];
    const float* b_e0   = (const float*)d_in[6];
    const float* W_e1   = (const float*)d_in[7];
    const float* a_s_e1 = (const float*)d_in[8];
    const float* a_d_e1 = (const float*)d_in[9];
    const float* b_e1   = (const float*)d_in[10];
    const float* W_d0   = (const float*)d_in[11];
    const float* a_s_d0 = (const float*)d_in[12];
    const float* a_d_d0 = (const float*)d_in[13];
    const float* b_d0   = (const float*)d_in[14];
    const float* W_d1   = (const float*)d_in[15];
    const float* a_s_d1 = (const float*)d_in[16];
    const float* a_d_d1 = (const float*)d_in[17];
    const float* b_d1   = (const float*)d_in[18];
    const float* g_w1   = (const float*)d_in[19];
    const float* g_b1   = (const float*)d_in[20];
    const float* g_w2   = (const float*)d_in[21];
    const float* g_b2   = (const float*)d_in[22];

    const int N    = in_sizes[2];
    const int E    = in_sizes[1] / 2;
    const int Etot = E + N;
    const int Din  = in_sizes[0] / N;  // 128

    char* w = (char*)d_ws;
    size_t o = 0;
    auto alloc = [&](size_t bytes) -> void* {
        void* p = w + o;
        o = (o + bytes + 255) & ~(size_t)255;
        return p;
    };
    __half*   h16    = (__half*)  alloc((size_t)N * 512 * 2);  // also z (dec1)
    __half*   x16    = (__half*)  alloc((size_t)N * Din * 2);
    __half*   bufA   = (__half*)  alloc((size_t)N * 64 * 2);
    __half*   bufB   = (__half*)  alloc((size_t)N * 64 * 2);
    __half*   wt_e0  = (__half*)  alloc((size_t)512 * 128 * 2);
    __half*   wt_e1  = (__half*)  alloc((size_t)512 * 64 * 2);
    __half*   wst_d1 = (__half*)  alloc((size_t)128 * 64 * 2);
    float*    ws_e0  = (float*)   alloc(8 * 128 * 4);
    float*    wd_e0  = (float*)   alloc(8 * 128 * 4);
    float*    ws_e1  = (float*)   alloc(8 * 64 * 4);
    float*    wd_e1  = (float*)   alloc(8 * 64 * 4);
    float*    ws_d1  = (float*)   alloc(64 * 4);
    float*    wd_d1  = (float*)   alloc(64 * 4);
    float*    es     = (float*)   alloc((size_t)N * 8 * 4);
    float*    ed     = (float*)   alloc((size_t)N * 8 * 4);
    float*    gate   = (float*)   alloc((size_t)N * 4);
    float*    pg     = (float*)   alloc((size_t)N * 4);
    int*      off    = (int*)     alloc((size_t)(N + 1) * 4);
    int*      cnt    = (int*)     alloc((size_t)N * 4);
    int*      esrc   = (int*)     alloc((size_t)Etot * 4);
    int*      bsum   = (int*)     alloc(256 * 4);
    int*      gstart = (int*)     alloc(17 * 4);
    unsigned* gm     = (unsigned*)alloc(16 * 4);
    float*    gden   = (float*)   alloc(16 * 4);
    float*    pooled = (float*)   alloc(16 * 64 * 4);
    float*    hd016  = (float*)   alloc(16 * 64 * 4);
    float*    es16   = (float*)   alloc(16 * 4);
    float*    ed16   = (float*)   alloc(16 * 4);
    (void)ws_size; (void)n_in; (void)out_size;

    const int nodeWaveGrid = cdiv(N, 4);
    const int edgeGrid     = cdiv(Etot, TB);
    const int scanBlocks   = cdiv(N, 256);

    // ---- CSR + graph ranges ----
    hipMemsetAsync(cnt, 0, (size_t)N * 4, stream);
    csr_count<<<edgeGrid, TB, 0, stream>>>(ei, E, Etot, cnt);
    scan_phase1<<<scanBlocks, 256, 0, stream>>>(cnt, esrc /*temp incl*/, bsum, N);
    scan_phase2<<<1, 256, 0, stream>>>(bsum, scanBlocks);
    scan_phase3<<<scanBlocks, 256, 0, stream>>>(esrc, bsum, off, N);
    hipMemsetAsync(cnt, 0, (size_t)N * 4, stream);
    csr_fill<<<edgeGrid, TB, 0, stream>>>(ei, E, Etot, off, cnt, esrc);
    find_gstart<<<cdiv(N, TB), TB, 0, stream>>>(batch, gstart, N);

    // ---- prep ----
    cast_f2h<<<cdiv(N * Din / 2, TB), TB, 0, stream>>>(x, x16, N * Din);
    transpose_cast<<<cdiv(512 * 128, TB), TB, 0, stream>>>(W_e0, wt_e0, Din, 512);
    transpose_cast<<<cdiv(512 * 64, TB), TB, 0, stream>>>(W_e1, wt_e1, 64, 512);
    make_wstackT<<<cdiv(128 * 64, TB), TB, 0, stream>>>(W_d1, wst_d1, 64, 1, 128);
    make_ws<<<cdiv(8 * 128, TB), TB, 0, stream>>>(W_e0, a_s_e0, a_d_e0, ws_e0, wd_e0, 128, 8, 64);
    make_ws<<<cdiv(8 * 64, TB), TB, 0, stream>>>(W_e1, a_s_e1, a_d_e1, ws_e1, wd_e1, 64, 8, 64);
    make_ws<<<1, TB, 0, stream>>>(W_d1, a_s_d1, a_d_d1, ws_d1, wd_d1, 64, 1, 128);

    // ---- encoder layer 0 (H=8, relu) ----
    scores_from_A<128, 8><<<nodeWaveGrid, TB, 0, stream>>>(x16, ws_e0, wd_e0, es, ed, N);
    {
        dim3 grid(512 / 64, cdiv(N, 64));
        gemm_mfma<128><<<grid, TB, 0, stream>>>(x16, wt_e0, h16, N, 512);
    }
    gat_gather_h<8, 64, true, __half><<<nodeWaveGrid, TB, 0, stream>>>(
        h16, es, ed, off, esrc, b_e0, bufA, N);

    // ---- encoder layer 1 (H=8, no relu) ----
    scores_from_A<64, 8><<<nodeWaveGrid, TB, 0, stream>>>(bufA, ws_e1, wd_e1, es, ed, N);
    {
        dim3 grid(512 / 64, cdiv(N, 64));
        gemm_mfma<64><<<grid, TB, 0, stream>>>(bufA, wt_e1, h16, N, 512);
    }
    gat_gather_h<8, 64, false, __half><<<nodeWaveGrid, TB, 0, stream>>>(
        h16, es, ed, off, esrc, b_e1, bufB, N);

    // ---- pooling ----
    hipMemsetAsync(gm, 0, 16 * 4, stream);
    hipMemsetAsync(gden, 0, 16 * 4, stream);
    hipMemsetAsync(pooled, 0, 16 * 64 * 4, stream);
    gate_kernel<<<nodeWaveGrid, TB, 0, stream>>>(bufB, g_w1, g_b1, g_w2, g_b2, gate, N);
    gmax_kernel<<<256, TB, 0, stream>>>(gate, batch, gm, N);
    pool_p<<<cdiv(N, TB), TB, 0, stream>>>(gate, gm, batch, pg, gden, N);
    {
        dim3 grid(16, POOL_SPLIT);
        pool_sum2<<<grid, TB, 0, stream>>>(bufB, pg, gstart, pooled, N);
    }
    dec_prep<<<16, 64, 0, stream>>>(pooled, gden, W_d0, a_s_d0, a_d_d0, hd016, es16, ed16);

    // ---- decoder layer 0 (H=1, relu) ----
    gat_gather_d0<<<nodeWaveGrid, TB, 0, stream>>>(
        hd016, es16, ed16, off, esrc, batch, b_d0, bufA, N);

    // ---- decoder layer 1 (H=1, C=128, no relu): z-path -> d_out ----
    scores_from_A<64, 1><<<nodeWaveGrid, TB, 0, stream>>>(bufA, ws_d1, wd_d1, es, ed, N);
    gat_gather_z<64, 1><<<nodeWaveGrid, TB, 0, stream>>>(bufA, es, ed, off, esrc, h16 /*z*/, N);
    {
        dim3 grid(2, cdiv(N, 64));
        gemm_kt<64, float, false><<<grid, TB, 0, stream>>>(h16 /*z*/, wst_d1, b_d1, (float*)d_out, N, 128);
    }
}

// Round 9
// 503.745 us; speedup vs baseline: 1.3108x; 1.0604x over previous
//
#include <hip/hip_runtime.h>
#include <hip/hip_fp16.h>
#include <math.h>

#define TB 256

typedef _Float16 half8v __attribute__((ext_vector_type(8)));
typedef float float4v __attribute__((ext_vector_type(4)));

static __device__ __forceinline__ unsigned f2o(float x) {
    unsigned b = __float_as_uint(x);
    return (b & 0x80000000u) ? ~b : (b | 0x80000000u);
}
static __device__ __forceinline__ float o2f(unsigned u) {
    return (u & 0x80000000u) ? __uint_as_float(u & 0x7FFFFFFFu) : __uint_as_float(~u);
}

static __device__ __forceinline__ int edge_src(const int* ei, int E, int e) {
    return (e < E) ? ei[e] : (e - E);
}
static __device__ __forceinline__ int edge_dst(const int* ei, int E, int e) {
    return (e < E) ? ei[E + e] : (e - E);
}

// ---------------- CSR build ----------------
__global__ void csr_count(const int* __restrict__ ei, int E, int Etot, int* __restrict__ cnt) {
    int e = blockIdx.x * blockDim.x + threadIdx.x;
    if (e >= Etot) return;
    atomicAdd(&cnt[edge_dst(ei, E, e)], 1);
}

__global__ __launch_bounds__(256) void scan_phase1(const int* __restrict__ cnt,
                                                   int* __restrict__ incl,
                                                   int* __restrict__ bsum, int n) {
    __shared__ int sdata[256];
    int t = threadIdx.x;
    int base = blockIdx.x * 256;
    int v = (base + t < n) ? cnt[base + t] : 0;
    for (int d = 1; d < 256; d <<= 1) {
        sdata[t] = v; __syncthreads();
        if (t >= d) v += sdata[t - d];
        __syncthreads();
    }
    if (base + t < n) incl[base + t] = v;
    if (t == 255) bsum[blockIdx.x] = v;
}

__global__ void scan_phase2(int* bsum, int nb) {
    __shared__ int sdata[256];
    int t = threadIdx.x;
    int v = (t < nb) ? bsum[t] : 0;
    for (int d = 1; d < 256; d <<= 1) {
        sdata[t] = v; __syncthreads();
        if (t >= d) v += sdata[t - d];
        __syncthreads();
    }
    if (t < nb) bsum[t] = v;
}

__global__ __launch_bounds__(256) void scan_phase3(const int* __restrict__ incl,
                                                   const int* __restrict__ bsum,
                                                   int* __restrict__ off, int n) {
    int i = blockIdx.x * 256 + threadIdx.x;
    if (i < n) off[i + 1] = incl[i] + (blockIdx.x ? bsum[blockIdx.x - 1] : 0);
    if (i == 0) off[0] = 0;
}

__global__ void csr_fill(const int* __restrict__ ei, int E, int Etot,
                         const int* __restrict__ off, int* __restrict__ cur,
                         int* __restrict__ esrc) {
    int e = blockIdx.x * blockDim.x + threadIdx.x;
    if (e >= Etot) return;
    int d = edge_dst(ei, E, e);
    int pos = atomicAdd(&cur[d], 1);
    esrc[off[d] + pos] = edge_src(ei, E, e);
}

// graph range table from sorted batch
__global__ void find_gstart(const int* __restrict__ batch, int* __restrict__ gstart, int N) {
    int n = blockIdx.x * blockDim.x + threadIdx.x;
    if (n >= N) return;
    int b = batch[n];
    int prev = n ? batch[n - 1] : -1;
    for (int g = prev + 1; g <= b; ++g) gstart[g] = n;
    if (n == N - 1)
        for (int g = b + 1; g <= 16; ++g) gstart[g] = N;
}

// ---------------- prep ----------------
__global__ void cast_f2h(const float* __restrict__ in, __half* __restrict__ out, int n) {
    int i2 = (blockIdx.x * blockDim.x + threadIdx.x) * 2;
    if (i2 + 1 < n) {
        float2 v = *(const float2*)(in + i2);
        *(__half2*)(out + i2) = __floats2half2_rn(v.x, v.y);
    } else if (i2 < n) {
        out[i2] = __float2half(in[i2]);
    }
}

__global__ void make_ws(const float* __restrict__ W, const float* __restrict__ a_s,
                        const float* __restrict__ a_d, float* __restrict__ ws,
                        float* __restrict__ wd, int K, int H, int C) {
    int i = blockIdx.x * blockDim.x + threadIdx.x;
    if (i >= H * K) return;
    int h = i / K, k = i % K;
    const float* wrow = W + (size_t)k * H * C + h * C;
    float s = 0.f, d = 0.f;
    for (int c = 0; c < C; ++c) {
        s += wrow[c] * a_s[h * C + c];
        d += wrow[c] * a_d[h * C + c];
    }
    ws[i] = s;
    wd[i] = d;
}

__global__ void transpose_cast(const float* __restrict__ W, __half* __restrict__ WT,
                               int K, int N) {
    int i = blockIdx.x * blockDim.x + threadIdx.x;
    if (i >= N * K) return;
    int nn = i / K, kk = i % K;
    WT[i] = __float2half(W[kk * N + nn]);
}

__global__ void make_wstackT(const float* __restrict__ W, __half* __restrict__ WT,
                             int K, int H, int C) {
    int i = blockIdx.x * blockDim.x + threadIdx.x;
    if (i >= K * H * C) return;
    int c = i / (H * K);
    int rem = i % (H * K);
    int h = rem / K, k = rem % K;
    WT[i] = __float2half(W[(size_t)k * H * C + h * C + c]);
}

// ---------------- MFMA GEMM (post-projection) ----------------
template <int K>
__global__ __launch_bounds__(256) void gemm_mfma(const __half* __restrict__ A,
                                                 const __half* __restrict__ BT,
                                                 __half* __restrict__ C,
                                                 int M, int N) {
    constexpr int KP = K + 8;
    __shared__ __align__(16) __half As[64 * KP];
    __shared__ __align__(16) __half Bs[64 * KP];
    int tid = threadIdx.x;
    int bm = blockIdx.y * 64, bn = blockIdx.x * 64;
    constexpr int LPR = K / 8;
    for (int idx = tid; idx < 64 * LPR; idx += 256) {
        int row = idx / LPR, koff = (idx % LPR) * 8;
        uint4 v = make_uint4(0u, 0u, 0u, 0u);
        int gr = bm + row;
        if (gr < M) v = *(const uint4*)(A + (size_t)gr * K + koff);
        *(uint4*)(&As[row * KP + koff]) = v;
        uint4 wv = *(const uint4*)(BT + (size_t)(bn + row) * K + koff);
        *(uint4*)(&Bs[row * KP + koff]) = wv;
    }
    __syncthreads();
    int wv_ = tid >> 6, l = tid & 63;
    int lr = l & 15, g = l >> 4;
    float4v acc[4] = {{0.f, 0.f, 0.f, 0.f}, {0.f, 0.f, 0.f, 0.f},
                      {0.f, 0.f, 0.f, 0.f}, {0.f, 0.f, 0.f, 0.f}};
    const __half* ap = &As[(16 * wv_ + lr) * KP + 8 * g];
    const __half* bp = &Bs[lr * KP + 8 * g];
#pragma unroll
    for (int k0 = 0; k0 < K; k0 += 32) {
        half8v af = *reinterpret_cast<const half8v*>(ap + k0);
#pragma unroll
        for (int nt = 0; nt < 4; ++nt) {
            half8v bf = *reinterpret_cast<const half8v*>(bp + nt * 16 * KP + k0);
            acc[nt] = __builtin_amdgcn_mfma_f32_16x16x32_f16(af, bf, acc[nt], 0, 0, 0);
        }
    }
#pragma unroll
    for (int nt = 0; nt < 4; ++nt) {
#pragma unroll
        for (int r = 0; r < 4; ++r) {
            int grow = bm + 16 * wv_ + 4 * g + r;
            if (grow < M)
                C[(size_t)grow * N + bn + nt * 16 + lr] = __float2half(acc[nt][r]);
        }
    }
}

// ---------------- scores directly from A ----------------
template <int K, int H>
__global__ __launch_bounds__(256) void scores_from_A(const __half* __restrict__ A,
                                                     const float* __restrict__ ws,
                                                     const float* __restrict__ wd,
                                                     float* __restrict__ es,
                                                     float* __restrict__ ed, int N) {
    constexpr int VPL = K / 64;
    int n = (blockIdx.x * blockDim.x + threadIdx.x) >> 6;
    int lane = threadIdx.x & 63;
    if (n >= N) return;
    float a[VPL];
    const __half* row = A + (size_t)n * K + lane * VPL;
    if constexpr (VPL == 2) {
        __half2 r = *(const __half2*)row;
        a[0] = __low2float(r);
        a[1] = __high2float(r);
    } else {
        a[0] = __half2float(row[0]);
    }
    float s[H], d[H];
#pragma unroll
    for (int h = 0; h < H; ++h) {
        s[h] = 0.f; d[h] = 0.f;
#pragma unroll
        for (int v = 0; v < VPL; ++v) {
            s[h] += a[v] * ws[h * K + lane * VPL + v];
            d[h] += a[v] * wd[h * K + lane * VPL + v];
        }
    }
#pragma unroll
    for (int o = 1; o < 64; o <<= 1) {
#pragma unroll
        for (int h = 0; h < H; ++h) {
            s[h] += __shfl_xor(s[h], o);
            d[h] += __shfl_xor(d[h], o);
        }
    }
    if (lane == 0) {
#pragma unroll
        for (int h = 0; h < H; ++h) {
            es[(size_t)n * H + h] = s[h];
            ed[(size_t)n * H + h] = d[h];
        }
    }
}

// ------- FUSED softmax + aggregation, 8-edge chunked (8-deep MLP) ------------
// H=8, C=64 only. Lane roles: alpha part k8=lane>>3 (edge), h8=lane&7 (head);
// gather part: lane owns 8 contiguous halfs of the 512-row, head hd=lane>>3.
template <bool RELU>
__global__ __launch_bounds__(256) void gat_gather_h8(const __half* __restrict__ hsrc,
                                                     const float* __restrict__ es,
                                                     const float* __restrict__ ed,
                                                     const int* __restrict__ off,
                                                     const int* __restrict__ esrc,
                                                     const float* __restrict__ bias,
                                                     __half* __restrict__ out, int N) {
    constexpr int HC = 512;
    int n = (blockIdx.x * blockDim.x + threadIdx.x) >> 6;
    int lane = threadIdx.x & 63;
    if (n >= N) return;
    int hd = lane >> 3;            // head of this lane's 8-half slice
    int k8 = lane >> 3, h8 = lane & 7;
    int j0 = off[n], j1 = off[n + 1];

    float edl = ed[(size_t)n * 8 + h8];

    float acc[8] = {};
    float denacc = 0.f;
    for (int j = j0; j < j1; j += 8) {
        int jj = j + k8;
        int jc = (jj < j1) ? jj : (j1 - 1);
        int sidx = esrc[jc];
        // logits for 8 edges x 8 heads in parallel
        float v = es[(size_t)sidx * 8 + h8] + edl;
        v = (v > 0.f) ? v : 0.2f * v;
        float pm = (jj < j1) ? expf(v) : 0.f;
        denacc += pm;
        // broadcast src ids, issue 8 independent row loads
        uint4 rw[8];
#pragma unroll
        for (int k = 0; k < 8; ++k) {
            int sb = __shfl(sidx, k * 8);
            rw[k] = *(const uint4*)(hsrc + (size_t)sb * HC + 8 * lane);
        }
#pragma unroll
        for (int k = 0; k < 8; ++k) {
            float a = __shfl(pm, k * 8 + hd);
            const __half* hv = (const __half*)&rw[k];
#pragma unroll
            for (int q = 0; q < 8; ++q) acc[q] += a * __half2float(hv[q]);
        }
    }

    // denominator: sum over edge-groups (lanes differing in bits 3..5)
    float den = denacc;
#pragma unroll
    for (int o = 8; o < 64; o <<= 1) den += __shfl_xor(den, o);
    float dv = __shfl(den, hd) + 1e-16f;

#pragma unroll
    for (int q = 0; q < 8; ++q) acc[q] /= dv;
    // sum heads: butterfly over lane bits >= 3
#pragma unroll
    for (int o = 8; o < 64; o <<= 1)
#pragma unroll
        for (int q = 0; q < 8; ++q) acc[q] += __shfl_xor(acc[q], o);

    if (lane < 8) {
        int cbase = 8 * lane;
        float r[8];
#pragma unroll
        for (int q = 0; q < 8; ++q) {
            float o2 = acc[q] * 0.125f + bias[cbase + q];
            if (RELU) o2 = fmaxf(o2, 0.f);
            r[q] = o2;
        }
        __half2 p0 = __floats2half2_rn(r[0], r[1]);
        __half2 p1 = __floats2half2_rn(r[2], r[3]);
        __half2 p2 = __floats2half2_rn(r[4], r[5]);
        __half2 p3 = __floats2half2_rn(r[6], r[7]);
        uint4 pk;
        pk.x = *(unsigned*)&p0; pk.y = *(unsigned*)&p1;
        pk.z = *(unsigned*)&p2; pk.w = *(unsigned*)&p3;
        *(uint4*)(out + (size_t)n * 64 + cbase) = pk;
    }
}

// -------- single-pass z-gather (pre-projection, dec1) ----------------
template <int K, int H>
__global__ __launch_bounds__(256) void gat_gather_z(const __half* __restrict__ A,
                                                    const float* __restrict__ es,
                                                    const float* __restrict__ ed,
                                                    const int* __restrict__ off,
                                                    const int* __restrict__ esrc,
                                                    __half* __restrict__ z, int N) {
    constexpr int VPL = K / 64;
    int n = (blockIdx.x * blockDim.x + threadIdx.x) >> 6;
    int lane = threadIdx.x & 63;
    if (n >= N) return;
    int j0 = off[n], j1 = off[n + 1];

    float ed_h = (lane < H) ? ed[(size_t)n * H + lane] : 0.f;

    float acc[H][VPL];
#pragma unroll
    for (int h = 0; h < H; ++h)
#pragma unroll
        for (int v = 0; v < VPL; ++v) acc[h][v] = 0.f;
    float den_h = 0.f;
    for (int j = j0; j < j1; ++j) {
        int s = esrc[j];
        float pm = 0.f;
        if (lane < H) {
            float v = es[(size_t)s * H + lane] + ed_h;
            v = (v > 0.f) ? v : 0.2f * v;
            pm = expf(v);
            den_h += pm;
        }
        float a[VPL];
        const __half* row = A + (size_t)s * K + lane * VPL;
        if constexpr (VPL == 2) {
            __half2 r = *(const __half2*)row;
            a[0] = __low2float(r);
            a[1] = __high2float(r);
        } else {
            a[0] = __half2float(row[0]);
        }
#pragma unroll
        for (int h = 0; h < H; ++h) {
            float al = __shfl(pm, h);
#pragma unroll
            for (int v = 0; v < VPL; ++v) acc[h][v] += al * a[v];
        }
    }

#pragma unroll
    for (int h = 0; h < H; ++h) {
        float inv = 1.f / ((__shfl(den_h, h) + 1e-16f) * H);
        __half* dst = z + (size_t)n * (H * K) + h * K + lane * VPL;
        if constexpr (VPL == 2) {
            *(__half2*)dst = __floats2half2_rn(acc[h][0] * inv, acc[h][1] * inv);
        } else {
            dst[0] = __float2half(acc[h][0] * inv);
        }
    }
}

// ---------------- K-tiled MFMA GEMM with bias/relu (z-path) ------------------
template <int KK, typename OUTT, bool RELU>
__global__ __launch_bounds__(256) void gemm_kt(const __half* __restrict__ A,
                                               const __half* __restrict__ BT,
                                               const float* __restrict__ bias,
                                               OUTT* __restrict__ C,
                                               int M, int Nout) {
    __shared__ __align__(16) __half As[64 * 72];
    __shared__ __align__(16) __half Bs[64 * 72];
    int tid = threadIdx.x;
    int bm = blockIdx.y * 64, bn = blockIdx.x * 64;
    int wv = tid >> 6, l = tid & 63, lr = l & 15, g = l >> 4;
    float4v acc[4] = {{0.f, 0.f, 0.f, 0.f}, {0.f, 0.f, 0.f, 0.f},
                      {0.f, 0.f, 0.f, 0.f}, {0.f, 0.f, 0.f, 0.f}};
    for (int kc = 0; kc < KK; kc += 64) {
        __syncthreads();
        for (int idx = tid; idx < 512; idx += 256) {
            int row = idx >> 3, ko = (idx & 7) * 8;
            uint4 v = make_uint4(0u, 0u, 0u, 0u);
            int gr = bm + row;
            if (gr < M) v = *(const uint4*)(A + (size_t)gr * KK + kc + ko);
            *(uint4*)(&As[row * 72 + ko]) = v;
            uint4 wvv = *(const uint4*)(BT + (size_t)(bn + row) * KK + kc + ko);
            *(uint4*)(&Bs[row * 72 + ko]) = wvv;
        }
        __syncthreads();
#pragma unroll
        for (int k0 = 0; k0 < 64; k0 += 32) {
            half8v af = *reinterpret_cast<const half8v*>(&As[(16 * wv + lr) * 72 + k0 + 8 * g]);
#pragma unroll
            for (int nt = 0; nt < 4; ++nt) {
                half8v bf = *reinterpret_cast<const half8v*>(&Bs[(nt * 16 + lr) * 72 + k0 + 8 * g]);
                acc[nt] = __builtin_amdgcn_mfma_f32_16x16x32_f16(af, bf, acc[nt], 0, 0, 0);
            }
        }
    }
#pragma unroll
    for (int nt = 0; nt < 4; ++nt) {
        float b = bias[bn + nt * 16 + lr];
#pragma unroll
        for (int r = 0; r < 4; ++r) {
            int grow = bm + 16 * wv + 4 * g + r;
            if (grow < M) {
                float c = acc[nt][r] + b;
                if (RELU) c = fmaxf(c, 0.f);
                if constexpr (sizeof(OUTT) == 2)
                    C[(size_t)grow * Nout + bn + nt * 16 + lr] = __float2half(c);
                else
                    C[(size_t)grow * Nout + bn + nt * 16 + lr] = c;
            }
        }
    }
}

// ------- dec0 gather: 16-row table, scores via batch lookup ------------------
__global__ __launch_bounds__(256) void gat_gather_d0(const float* __restrict__ hsrc,
                                                     const float* __restrict__ es16,
                                                     const float* __restrict__ ed16,
                                                     const int* __restrict__ off,
                                                     const int* __restrict__ esrc,
                                                     const int* __restrict__ batch,
                                                     const float* __restrict__ bias,
                                                     __half* __restrict__ out, int N) {
    int n = (blockIdx.x * blockDim.x + threadIdx.x) >> 6;
    int lane = threadIdx.x & 63;
    if (n >= N) return;
    int j0 = off[n], j1 = off[n + 1];
    float ed_v = ed16[batch[n]];
    float acc = 0.f, den = 0.f;
    for (int j = j0; j < j1; ++j) {
        int s = esrc[j];
        int g = batch[s];
        float v = es16[g] + ed_v;
        v = (v > 0.f) ? v : 0.2f * v;
        float pm = expf(v);
        den += pm;
        acc += pm * hsrc[(size_t)g * 64 + lane];
    }
    float o = acc / (den + 1e-16f) + bias[lane];
    o = fmaxf(o, 0.f);
    out[(size_t)n * 64 + lane] = __float2half(o);
}

// ---------------- pooling ----------------
__global__ __launch_bounds__(256) void gate_kernel(const __half* __restrict__ h,
                                                   const float* __restrict__ w1,
                                                   const float* __restrict__ b1,
                                                   const float* __restrict__ w2,
                                                   const float* __restrict__ b2,
                                                   float* __restrict__ gate, int N) {
    int n = (blockIdx.x * blockDim.x + threadIdx.x) >> 6;
    int lane = threadIdx.x & 63;
    if (n >= N) return;
    float hv = __half2float(h[(size_t)n * 64 + lane]);
    float t = b1[lane];
    for (int c = 0; c < 64; ++c) t += __shfl(hv, c) * w1[c * 64 + lane];
    t = fmaxf(t, 0.f);
    float g = t * w2[lane];
#pragma unroll
    for (int o = 32; o; o >>= 1) g += __shfl_xor(g, o);
    g += b2[0];
    if (lane == 0) gate[n] = g;
}

__global__ __launch_bounds__(256) void gmax_kernel(const float* __restrict__ gate,
                                                   const int* __restrict__ batch,
                                                   unsigned* __restrict__ gm, int N) {
    __shared__ unsigned smax[16];
    int t = threadIdx.x;
    if (t < 16) smax[t] = 0u;
    __syncthreads();
    for (int i = blockIdx.x * blockDim.x + t; i < N; i += gridDim.x * blockDim.x)
        atomicMax(&smax[batch[i]], f2o(gate[i]));
    __syncthreads();
    if (t < 16 && smax[t]) atomicMax(&gm[t], smax[t]);
}

__global__ __launch_bounds__(256) void pool_p(const float* __restrict__ gate,
                                              const unsigned* __restrict__ gm,
                                              const int* __restrict__ batch,
                                              float* __restrict__ pg,
                                              float* __restrict__ gden, int N) {
    __shared__ float part[16];
    int t = threadIdx.x;
    if (t < 16) part[t] = 0.f;
    __syncthreads();
    int n = blockIdx.x * blockDim.x + t;
    if (n < N) {
        int b = batch[n];
        unsigned u = gm[b];
        float mf = u ? o2f(u) : 0.f;
        float p = expf(gate[n] - mf);
        pg[n] = p;
        atomicAdd(&part[b], p);
    }
    __syncthreads();
    if (t < 16 && part[t] != 0.f) atomicAdd(&gden[t], part[t]);
}

#define POOL_SPLIT 32
__global__ __launch_bounds__(256) void pool_sum2(const __half* __restrict__ h,
                                                 const float* __restrict__ pg,
                                                 const int* __restrict__ gstart,
                                                 float* __restrict__ pooled, int N) {
    __shared__ float part[256];
    int g = blockIdx.x;
    int r0 = gstart[g], r1 = gstart[g + 1];
    int len = r1 - r0;
    int chunk = (len + POOL_SPLIT - 1) / POOL_SPLIT;
    int s0 = r0 + blockIdx.y * chunk;
    int s1 = min(s0 + chunk, r1);
    int wv = threadIdx.x >> 6, lane = threadIdx.x & 63;
    float acc = 0.f;
    for (int n = s0 + wv; n < s1; n += 4)
        acc += pg[n] * __half2float(h[(size_t)n * 64 + lane]);
    part[threadIdx.x] = acc;
    __syncthreads();
    if (threadIdx.x < 64) {
        float tot = part[threadIdx.x] + part[64 + threadIdx.x] +
                    part[128 + threadIdx.x] + part[192 + threadIdx.x];
        if (tot != 0.f) atomicAdd(&pooled[g * 64 + threadIdx.x], tot);
    }
}

__global__ void dec_prep(const float* __restrict__ pooled, const float* __restrict__ gden,
                         const float* __restrict__ Wd0, const float* __restrict__ asd,
                         const float* __restrict__ add, float* __restrict__ hd016,
                         float* __restrict__ es16, float* __restrict__ ed16) {
    int g = blockIdx.x;
    int lane = threadIdx.x;
    float pn = pooled[g * 64 + lane] / (gden[g] + 1e-16f);
    float o = 0.f;
    for (int c = 0; c < 64; ++c) o += __shfl(pn, c) * Wd0[c * 64 + lane];
    hd016[g * 64 + lane] = o;
    float s = o * asd[lane], d = o * add[lane];
#pragma unroll
    for (int off = 32; off; off >>= 1) {
        s += __shfl_xor(s, off);
        d += __shfl_xor(d, off);
    }
    if (lane == 0) {
        es16[g] = s;
        ed16[g] = d;
    }
}

// ---------------- host ----------------
static inline int cdiv(int a, int b) { return (a + b - 1) / b; }

extern "C" void kernel_launch(void* const* d_in, const int* in_sizes, int n_in,
                              void* d_out, int out_size, void* d_ws, size_t ws_size,
                              hipStream_t stream) {
    const float* x      = (const float*)d_in[0];
    const int*   ei     = (const int*)  d_in[1];
    const int*   batch  = (const int*)  d_in[2];
    const float* W_e0   = (const float*)d_in[3];
    const float* a_s_e0 = (const float*)d_in[4];
    const float* a_d_e0 = (const float*)d_in[5];
    const float* b_e0   = (const float*)d_in[6];
    const float* W_e1   = (const float*)d_in[7];
    const float* a_s_e1 = (const float*)d_in[8];
    const float* a_d_e1 = (const float*)d_in[9];
    const float* b_e1   = (const float*)d_in[10];
    const float* W_d0   = (const float*)d_in[11];
    const float* a_s_d0 = (const float*)d_in[12];
    const float* a_d_d0 = (const float*)d_in[13];
    const float* b_d0   = (const float*)d_in[14];
    const float* W_d1   = (const float*)d_in[15];
    const float* a_s_d1 = (const float*)d_in[16];
    const float* a_d_d1 = (const float*)d_in[17];
    const float* b_d1   = (const float*)d_in[18];
    const float* g_w1   = (const float*)d_in[19];
    const float* g_b1   = (const float*)d_in[20];
    const float* g_w2   = (const float*)d_in[21];
    const float* g_b2   = (const float*)d_in[22];

    const int N    = in_sizes[2];
    const int E    = in_sizes[1] / 2;
    const int Etot = E + N;
    const int Din  = in_sizes[0] / N;  // 128

    char* w = (char*)d_ws;
    size_t o = 0;
    auto alloc = [&](size_t bytes) -> void* {
        void* p = w + o;
        o = (o + bytes + 255) & ~(size_t)255;
        return p;
    };
    __half*   h16    = (__half*)  alloc((size_t)N * 512 * 2);  // also z (dec1)
    __half*   x16    = (__half*)  alloc((size_t)N * Din * 2);
    __half*   bufA   = (__half*)  alloc((size_t)N * 64 * 2);
    __half*   bufB   = (__half*)  alloc((size_t)N * 64 * 2);
    __half*   wt_e0  = (__half*)  alloc((size_t)512 * 128 * 2);
    __half*   wt_e1  = (__half*)  alloc((size_t)512 * 64 * 2);
    __half*   wst_d1 = (__half*)  alloc((size_t)128 * 64 * 2);
    float*    ws_e0  = (float*)   alloc(8 * 128 * 4);
    float*    wd_e0  = (float*)   alloc(8 * 128 * 4);
    float*    ws_e1  = (float*)   alloc(8 * 64 * 4);
    float*    wd_e1  = (float*)   alloc(8 * 64 * 4);
    float*    ws_d1  = (float*)   alloc(64 * 4);
    float*    wd_d1  = (float*)   alloc(64 * 4);
    float*    es     = (float*)   alloc((size_t)N * 8 * 4);
    float*    ed     = (float*)   alloc((size_t)N * 8 * 4);
    float*    gate   = (float*)   alloc((size_t)N * 4);
    float*    pg     = (float*)   alloc((size_t)N * 4);
    int*      off    = (int*)     alloc((size_t)(N + 1) * 4);
    int*      cnt    = (int*)     alloc((size_t)N * 4);
    int*      esrc   = (int*)     alloc((size_t)Etot * 4);
    int*      bsum   = (int*)     alloc(256 * 4);
    int*      gstart = (int*)     alloc(17 * 4);
    unsigned* gm     = (unsigned*)alloc(16 * 4);
    float*    gden   = (float*)   alloc(16 * 4);
    float*    pooled = (float*)   alloc(16 * 64 * 4);
    float*    hd016  = (float*)   alloc(16 * 64 * 4);
    float*    es16   = (float*)   alloc(16 * 4);
    float*    ed16   = (float*)   alloc(16 * 4);
    (void)ws_size; (void)n_in; (void)out_size;

    const int nodeWaveGrid = cdiv(N, 4);
    const int edgeGrid     = cdiv(Etot, TB);
    const int scanBlocks   = cdiv(N, 256);

    // ---- CSR + graph ranges ----
    hipMemsetAsync(cnt, 0, (size_t)N * 4, stream);
    csr_count<<<edgeGrid, TB, 0, stream>>>(ei, E, Etot, cnt);
    scan_phase1<<<scanBlocks, 256, 0, stream>>>(cnt, esrc /*temp incl*/, bsum, N);
    scan_phase2<<<1, 256, 0, stream>>>(bsum, scanBlocks);
    scan_phase3<<<scanBlocks, 256, 0, stream>>>(esrc, bsum, off, N);
    hipMemsetAsync(cnt, 0, (size_t)N * 4, stream);
    csr_fill<<<edgeGrid, TB, 0, stream>>>(ei, E, Etot, off, cnt, esrc);
    find_gstart<<<cdiv(N, TB), TB, 0, stream>>>(batch, gstart, N);

    // ---- prep ----
    cast_f2h<<<cdiv(N * Din / 2, TB), TB, 0, stream>>>(x, x16, N * Din);
    transpose_cast<<<cdiv(512 * 128, TB), TB, 0, stream>>>(W_e0, wt_e0, Din, 512);
    transpose_cast<<<cdiv(512 * 64, TB), TB, 0, stream>>>(W_e1, wt_e1, 64, 512);
    make_wstackT<<<cdiv(128 * 64, TB), TB, 0, stream>>>(W_d1, wst_d1, 64, 1, 128);
    make_ws<<<cdiv(8 * 128, TB), TB, 0, stream>>>(W_e0, a_s_e0, a_d_e0, ws_e0, wd_e0, 128, 8, 64);
    make_ws<<<cdiv(8 * 64, TB), TB, 0, stream>>>(W_e1, a_s_e1, a_d_e1, ws_e1, wd_e1, 64, 8, 64);
    make_ws<<<1, TB, 0, stream>>>(W_d1, a_s_d1, a_d_d1, ws_d1, wd_d1, 64, 1, 128);

    // ---- encoder layer 0 (H=8, relu) ----
    scores_from_A<128, 8><<<nodeWaveGrid, TB, 0, stream>>>(x16, ws_e0, wd_e0, es, ed, N);
    {
        dim3 grid(512 / 64, cdiv(N, 64));
        gemm_mfma<128><<<grid, TB, 0, stream>>>(x16, wt_e0, h16, N, 512);
    }
    gat_gather_h8<true><<<nodeWaveGrid, TB, 0, stream>>>(
        h16, es, ed, off, esrc, b_e0, bufA, N);

    // ---- encoder layer 1 (H=8, no relu) ----
    scores_from_A<64, 8><<<nodeWaveGrid, TB, 0, stream>>>(bufA, ws_e1, wd_e1, es, ed, N);
    {
        dim3 grid(512 / 64, cdiv(N, 64));
        gemm_mfma<64><<<grid, TB, 0, stream>>>(bufA, wt_e1, h16, N, 512);
    }
    gat_gather_h8<false><<<nodeWaveGrid, TB, 0, stream>>>(
        h16, es, ed, off, esrc, b_e1, bufB, N);

    // ---- pooling ----
    hipMemsetAsync(gm, 0, 16 * 4, stream);
    hipMemsetAsync(gden, 0, 16 * 4, stream);
    hipMemsetAsync(pooled, 0, 16 * 64 * 4, stream);
    gate_kernel<<<nodeWaveGrid, TB, 0, stream>>>(bufB, g_w1, g_b1, g_w2, g_b2, gate, N);
    gmax_kernel<<<256, TB, 0, stream>>>(gate, batch, gm, N);
    pool_p<<<cdiv(N, TB), TB, 0, stream>>>(gate, gm, batch, pg, gden, N);
    {
        dim3 grid(16, POOL_SPLIT);
        pool_sum2<<<grid, TB, 0, stream>>>(bufB, pg, gstart, pooled, N);
    }
    dec_prep<<<16, 64, 0, stream>>>(pooled, gden, W_d0, a_s_d0, a_d_d0, hd016, es16, ed16);

    // ---- decoder layer 0 (H=1, relu) ----
    gat_gather_d0<<<nodeWaveGrid, TB, 0, stream>>>(
        hd016, es16, ed16, off, esrc, batch, b_d0, bufA, N);

    // ---- decoder layer 1 (H=1, C=128, no relu): z-path -> d_out ----
    scores_from_A<64, 1><<<nodeWaveGrid, TB, 0, stream>>>(bufA, ws_d1, wd_d1, es, ed, N);
    gat_gather_z<64, 1><<<nodeWaveGrid, TB, 0, stream>>>(bufA, es, ed, off, esrc, h16 /*z*/, N);
    {
        dim3 grid(2, cdiv(N, 64));
        gemm_kt<64, float, false><<<grid, TB, 0, stream>>>(h16 /*z*/, wst_d1, b_d1, (float*)d_out, N, 128);
    }
}

// Round 10
// 444.077 us; speedup vs baseline: 1.4870x; 1.1344x over previous
//
#include <hip/hip_runtime.h>
#include <hip/hip_fp16.h>
#include <math.h>

#define TB 256

typedef _Float16 half8v __attribute__((ext_vector_type(8)));
typedef float float4v __attribute__((ext_vector_type(4)));

static __device__ __forceinline__ unsigned f2o(float x) {
    unsigned b = __float_as_uint(x);
    return (b & 0x80000000u) ? ~b : (b | 0x80000000u);
}
static __device__ __forceinline__ float o2f(unsigned u) {
    return (u & 0x80000000u) ? __uint_as_float(u & 0x7FFFFFFFu) : __uint_as_float(~u);
}

static __device__ __forceinline__ int edge_src(const int* ei, int E, int e) {
    return (e < E) ? ei[e] : (e - E);
}
static __device__ __forceinline__ int edge_dst(const int* ei, int E, int e) {
    return (e < E) ? ei[E + e] : (e - E);
}

// ---------------- CSR build ----------------
__global__ void csr_count(const int* __restrict__ ei, int E, int Etot, int* __restrict__ cnt) {
    int e = blockIdx.x * blockDim.x + threadIdx.x;
    if (e >= Etot) return;
    atomicAdd(&cnt[edge_dst(ei, E, e)], 1);
}

__global__ __launch_bounds__(256) void scan_phase1(const int* __restrict__ cnt,
                                                   int* __restrict__ incl,
                                                   int* __restrict__ bsum, int n) {
    __shared__ int sdata[256];
    int t = threadIdx.x;
    int base = blockIdx.x * 256;
    int v = (base + t < n) ? cnt[base + t] : 0;
    for (int d = 1; d < 256; d <<= 1) {
        sdata[t] = v; __syncthreads();
        if (t >= d) v += sdata[t - d];
        __syncthreads();
    }
    if (base + t < n) incl[base + t] = v;
    if (t == 255) bsum[blockIdx.x] = v;
}

__global__ void scan_phase2(int* bsum, int nb) {
    __shared__ int sdata[256];
    int t = threadIdx.x;
    int v = (t < nb) ? bsum[t] : 0;
    for (int d = 1; d < 256; d <<= 1) {
        sdata[t] = v; __syncthreads();
        if (t >= d) v += sdata[t - d];
        __syncthreads();
    }
    if (t < nb) bsum[t] = v;
}

__global__ __launch_bounds__(256) void scan_phase3(const int* __restrict__ incl,
                                                   const int* __restrict__ bsum,
                                                   int* __restrict__ off, int n) {
    int i = blockIdx.x * 256 + threadIdx.x;
    if (i < n) off[i + 1] = incl[i] + (blockIdx.x ? bsum[blockIdx.x - 1] : 0);
    if (i == 0) off[0] = 0;
}

__global__ void csr_fill(const int* __restrict__ ei, int E, int Etot,
                         const int* __restrict__ off, int* __restrict__ cur,
                         int* __restrict__ esrc) {
    int e = blockIdx.x * blockDim.x + threadIdx.x;
    if (e >= Etot) return;
    int d = edge_dst(ei, E, e);
    int pos = atomicAdd(&cur[d], 1);
    esrc[off[d] + pos] = edge_src(ei, E, e);
}

// graph range table from sorted batch
__global__ void find_gstart(const int* __restrict__ batch, int* __restrict__ gstart, int N) {
    int n = blockIdx.x * blockDim.x + threadIdx.x;
    if (n >= N) return;
    int b = batch[n];
    int prev = n ? batch[n - 1] : -1;
    for (int g = prev + 1; g <= b; ++g) gstart[g] = n;
    if (n == N - 1)
        for (int g = b + 1; g <= 16; ++g) gstart[g] = N;
}

// ---------------- prep ----------------
__global__ void cast_f2h(const float* __restrict__ in, __half* __restrict__ out, int n) {
    int i2 = (blockIdx.x * blockDim.x + threadIdx.x) * 2;
    if (i2 + 1 < n) {
        float2 v = *(const float2*)(in + i2);
        *(__half2*)(out + i2) = __floats2half2_rn(v.x, v.y);
    } else if (i2 < n) {
        out[i2] = __float2half(in[i2]);
    }
}

__global__ void make_ws(const float* __restrict__ W, const float* __restrict__ a_s,
                        const float* __restrict__ a_d, float* __restrict__ ws,
                        float* __restrict__ wd, int K, int H, int C) {
    int i = blockIdx.x * blockDim.x + threadIdx.x;
    if (i >= H * K) return;
    int h = i / K, k = i % K;
    const float* wrow = W + (size_t)k * H * C + h * C;
    float s = 0.f, d = 0.f;
    for (int c = 0; c < C; ++c) {
        s += wrow[c] * a_s[h * C + c];
        d += wrow[c] * a_d[h * C + c];
    }
    ws[i] = s;
    wd[i] = d;
}

__global__ void transpose_cast(const float* __restrict__ W, __half* __restrict__ WT,
                               int K, int N) {
    int i = blockIdx.x * blockDim.x + threadIdx.x;
    if (i >= N * K) return;
    int nn = i / K, kk = i % K;
    WT[i] = __float2half(W[kk * N + nn]);
}

__global__ void make_wstackT(const float* __restrict__ W, __half* __restrict__ WT,
                             int K, int H, int C) {
    int i = blockIdx.x * blockDim.x + threadIdx.x;
    if (i >= K * H * C) return;
    int c = i / (H * K);
    int rem = i % (H * K);
    int h = rem / K, k = rem % K;
    WT[i] = __float2half(W[(size_t)k * H * C + h * C + c]);
}

// ---------------- MFMA GEMM (post-projection) ----------------
template <int K>
__global__ __launch_bounds__(256) void gemm_mfma(const __half* __restrict__ A,
                                                 const __half* __restrict__ BT,
                                                 __half* __restrict__ C,
                                                 int M, int N) {
    constexpr int KP = K + 8;
    __shared__ __align__(16) __half As[64 * KP];
    __shared__ __align__(16) __half Bs[64 * KP];
    int tid = threadIdx.x;
    int bm = blockIdx.y * 64, bn = blockIdx.x * 64;
    constexpr int LPR = K / 8;
    for (int idx = tid; idx < 64 * LPR; idx += 256) {
        int row = idx / LPR, koff = (idx % LPR) * 8;
        uint4 v = make_uint4(0u, 0u, 0u, 0u);
        int gr = bm + row;
        if (gr < M) v = *(const uint4*)(A + (size_t)gr * K + koff);
        *(uint4*)(&As[row * KP + koff]) = v;
        uint4 wv = *(const uint4*)(BT + (size_t)(bn + row) * K + koff);
        *(uint4*)(&Bs[row * KP + koff]) = wv;
    }
    __syncthreads();
    int wv_ = tid >> 6, l = tid & 63;
    int lr = l & 15, g = l >> 4;
    float4v acc[4] = {{0.f, 0.f, 0.f, 0.f}, {0.f, 0.f, 0.f, 0.f},
                      {0.f, 0.f, 0.f, 0.f}, {0.f, 0.f, 0.f, 0.f}};
    const __half* ap = &As[(16 * wv_ + lr) * KP + 8 * g];
    const __half* bp = &Bs[lr * KP + 8 * g];
#pragma unroll
    for (int k0 = 0; k0 < K; k0 += 32) {
        half8v af = *reinterpret_cast<const half8v*>(ap + k0);
#pragma unroll
        for (int nt = 0; nt < 4; ++nt) {
            half8v bf = *reinterpret_cast<const half8v*>(bp + nt * 16 * KP + k0);
            acc[nt] = __builtin_amdgcn_mfma_f32_16x16x32_f16(af, bf, acc[nt], 0, 0, 0);
        }
    }
#pragma unroll
    for (int nt = 0; nt < 4; ++nt) {
#pragma unroll
        for (int r = 0; r < 4; ++r) {
            int grow = bm + 16 * wv_ + 4 * g + r;
            if (grow < M)
                C[(size_t)grow * N + bn + nt * 16 + lr] = __float2half(acc[nt][r]);
        }
    }
}

// ------- scores, thread-per-node (no shuffles): es[n][h] = A[n] . ws[h] ------
template <int K, int H>
__global__ __launch_bounds__(256) void scores_nt(const __half* __restrict__ A,
                                                 const float* __restrict__ ws,
                                                 const float* __restrict__ wd,
                                                 float* __restrict__ es,
                                                 float* __restrict__ ed, int N) {
    int n = blockIdx.x * blockDim.x + threadIdx.x;
    if (n >= N) return;
    const __half* row = A + (size_t)n * K;
    float s[H] = {}, d[H] = {};
#pragma unroll
    for (int k0 = 0; k0 < K; k0 += 8) {
        uint4 raw = *(const uint4*)(row + k0);
        const __half* hv = (const __half*)&raw;
        float a[8];
#pragma unroll
        for (int q = 0; q < 8; ++q) a[q] = __half2float(hv[q]);
#pragma unroll
        for (int h = 0; h < H; ++h)
#pragma unroll
            for (int q = 0; q < 8; ++q) {
                s[h] += a[q] * ws[h * K + k0 + q];
                d[h] += a[q] * wd[h * K + k0 + q];
            }
    }
#pragma unroll
    for (int h = 0; h < H; ++h) {
        es[(size_t)n * H + h] = s[h];
        ed[(size_t)n * H + h] = d[h];
    }
}

// ------- FUSED softmax + aggregation, 8-edge chunked (8-deep MLP) ------------
template <bool RELU>
__global__ __launch_bounds__(256) void gat_gather_h8(const __half* __restrict__ hsrc,
                                                     const float* __restrict__ es,
                                                     const float* __restrict__ ed,
                                                     const int* __restrict__ off,
                                                     const int* __restrict__ esrc,
                                                     const float* __restrict__ bias,
                                                     __half* __restrict__ out, int N) {
    constexpr int HC = 512;
    int n = (blockIdx.x * blockDim.x + threadIdx.x) >> 6;
    int lane = threadIdx.x & 63;
    if (n >= N) return;
    int hd = lane >> 3;
    int k8 = lane >> 3, h8 = lane & 7;
    int j0 = off[n], j1 = off[n + 1];

    float edl = ed[(size_t)n * 8 + h8];

    float acc[8] = {};
    float denacc = 0.f;
    for (int j = j0; j < j1; j += 8) {
        int jj = j + k8;
        int jc = (jj < j1) ? jj : (j1 - 1);
        int sidx = esrc[jc];
        float v = es[(size_t)sidx * 8 + h8] + edl;
        v = (v > 0.f) ? v : 0.2f * v;
        float pm = (jj < j1) ? expf(v) : 0.f;
        denacc += pm;
        uint4 rw[8];
#pragma unroll
        for (int k = 0; k < 8; ++k) {
            int sb = __shfl(sidx, k * 8);
            rw[k] = *(const uint4*)(hsrc + (size_t)sb * HC + 8 * lane);
        }
#pragma unroll
        for (int k = 0; k < 8; ++k) {
            float a = __shfl(pm, k * 8 + hd);
            const __half* hv = (const __half*)&rw[k];
#pragma unroll
            for (int q = 0; q < 8; ++q) acc[q] += a * __half2float(hv[q]);
        }
    }

    float den = denacc;
#pragma unroll
    for (int o = 8; o < 64; o <<= 1) den += __shfl_xor(den, o);
    float dv = __shfl(den, hd) + 1e-16f;

#pragma unroll
    for (int q = 0; q < 8; ++q) acc[q] /= dv;
#pragma unroll
    for (int o = 8; o < 64; o <<= 1)
#pragma unroll
        for (int q = 0; q < 8; ++q) acc[q] += __shfl_xor(acc[q], o);

    if (lane < 8) {
        int cbase = 8 * lane;
        float r[8];
#pragma unroll
        for (int q = 0; q < 8; ++q) {
            float o2 = acc[q] * 0.125f + bias[cbase + q];
            if (RELU) o2 = fmaxf(o2, 0.f);
            r[q] = o2;
        }
        __half2 p0 = __floats2half2_rn(r[0], r[1]);
        __half2 p1 = __floats2half2_rn(r[2], r[3]);
        __half2 p2 = __floats2half2_rn(r[4], r[5]);
        __half2 p3 = __floats2half2_rn(r[6], r[7]);
        uint4 pk;
        pk.x = *(unsigned*)&p0; pk.y = *(unsigned*)&p1;
        pk.z = *(unsigned*)&p2; pk.w = *(unsigned*)&p3;
        *(uint4*)(out + (size_t)n * 64 + cbase) = pk;
    }
}

// -------- single-pass z-gather (pre-projection, dec1) ----------------
template <int K, int H>
__global__ __launch_bounds__(256) void gat_gather_z(const __half* __restrict__ A,
                                                    const float* __restrict__ es,
                                                    const float* __restrict__ ed,
                                                    const int* __restrict__ off,
                                                    const int* __restrict__ esrc,
                                                    __half* __restrict__ z, int N) {
    constexpr int VPL = K / 64;
    int n = (blockIdx.x * blockDim.x + threadIdx.x) >> 6;
    int lane = threadIdx.x & 63;
    if (n >= N) return;
    int j0 = off[n], j1 = off[n + 1];

    float ed_h = (lane < H) ? ed[(size_t)n * H + lane] : 0.f;

    float acc[H][VPL];
#pragma unroll
    for (int h = 0; h < H; ++h)
#pragma unroll
        for (int v = 0; v < VPL; ++v) acc[h][v] = 0.f;
    float den_h = 0.f;
    for (int j = j0; j < j1; ++j) {
        int s = esrc[j];
        float pm = 0.f;
        if (lane < H) {
            float v = es[(size_t)s * H + lane] + ed_h;
            v = (v > 0.f) ? v : 0.2f * v;
            pm = expf(v);
            den_h += pm;
        }
        float a[VPL];
        const __half* row = A + (size_t)s * K + lane * VPL;
        if constexpr (VPL == 2) {
            __half2 r = *(const __half2*)row;
            a[0] = __low2float(r);
            a[1] = __high2float(r);
        } else {
            a[0] = __half2float(row[0]);
        }
#pragma unroll
        for (int h = 0; h < H; ++h) {
            float al = __shfl(pm, h);
#pragma unroll
            for (int v = 0; v < VPL; ++v) acc[h][v] += al * a[v];
        }
    }

#pragma unroll
    for (int h = 0; h < H; ++h) {
        float inv = 1.f / ((__shfl(den_h, h) + 1e-16f) * H);
        __half* dst = z + (size_t)n * (H * K) + h * K + lane * VPL;
        if constexpr (VPL == 2) {
            *(__half2*)dst = __floats2half2_rn(acc[h][0] * inv, acc[h][1] * inv);
        } else {
            dst[0] = __float2half(acc[h][0] * inv);
        }
    }
}

// ---------------- K-tiled MFMA GEMM with bias/relu (z-path) ------------------
template <int KK, typename OUTT, bool RELU>
__global__ __launch_bounds__(256) void gemm_kt(const __half* __restrict__ A,
                                               const __half* __restrict__ BT,
                                               const float* __restrict__ bias,
                                               OUTT* __restrict__ C,
                                               int M, int Nout) {
    __shared__ __align__(16) __half As[64 * 72];
    __shared__ __align__(16) __half Bs[64 * 72];
    int tid = threadIdx.x;
    int bm = blockIdx.y * 64, bn = blockIdx.x * 64;
    int wv = tid >> 6, l = tid & 63, lr = l & 15, g = l >> 4;
    float4v acc[4] = {{0.f, 0.f, 0.f, 0.f}, {0.f, 0.f, 0.f, 0.f},
                      {0.f, 0.f, 0.f, 0.f}, {0.f, 0.f, 0.f, 0.f}};
    for (int kc = 0; kc < KK; kc += 64) {
        __syncthreads();
        for (int idx = tid; idx < 512; idx += 256) {
            int row = idx >> 3, ko = (idx & 7) * 8;
            uint4 v = make_uint4(0u, 0u, 0u, 0u);
            int gr = bm + row;
            if (gr < M) v = *(const uint4*)(A + (size_t)gr * KK + kc + ko);
            *(uint4*)(&As[row * 72 + ko]) = v;
            uint4 wvv = *(const uint4*)(BT + (size_t)(bn + row) * KK + kc + ko);
            *(uint4*)(&Bs[row * 72 + ko]) = wvv;
        }
        __syncthreads();
#pragma unroll
        for (int k0 = 0; k0 < 64; k0 += 32) {
            half8v af = *reinterpret_cast<const half8v*>(&As[(16 * wv + lr) * 72 + k0 + 8 * g]);
#pragma unroll
            for (int nt = 0; nt < 4; ++nt) {
                half8v bf = *reinterpret_cast<const half8v*>(&Bs[(nt * 16 + lr) * 72 + k0 + 8 * g]);
                acc[nt] = __builtin_amdgcn_mfma_f32_16x16x32_f16(af, bf, acc[nt], 0, 0, 0);
            }
        }
    }
#pragma unroll
    for (int nt = 0; nt < 4; ++nt) {
        float b = bias[bn + nt * 16 + lr];
#pragma unroll
        for (int r = 0; r < 4; ++r) {
            int grow = bm + 16 * wv + 4 * g + r;
            if (grow < M) {
                float c = acc[nt][r] + b;
                if (RELU) c = fmaxf(c, 0.f);
                if constexpr (sizeof(OUTT) == 2)
                    C[(size_t)grow * Nout + bn + nt * 16 + lr] = __float2half(c);
                else
                    C[(size_t)grow * Nout + bn + nt * 16 + lr] = c;
            }
        }
    }
}

// ------- dec0 gather: 16-row table, scores via batch lookup ------------------
__global__ __launch_bounds__(256) void gat_gather_d0(const float* __restrict__ hsrc,
                                                     const float* __restrict__ es16,
                                                     const float* __restrict__ ed16,
                                                     const int* __restrict__ off,
                                                     const int* __restrict__ esrc,
                                                     const int* __restrict__ batch,
                                                     const float* __restrict__ bias,
                                                     __half* __restrict__ out, int N) {
    int n = (blockIdx.x * blockDim.x + threadIdx.x) >> 6;
    int lane = threadIdx.x & 63;
    if (n >= N) return;
    int j0 = off[n], j1 = off[n + 1];
    float ed_v = ed16[batch[n]];
    float acc = 0.f, den = 0.f;
    for (int j = j0; j < j1; ++j) {
        int s = esrc[j];
        int g = batch[s];
        float v = es16[g] + ed_v;
        v = (v > 0.f) ? v : 0.2f * v;
        float pm = expf(v);
        den += pm;
        acc += pm * hsrc[(size_t)g * 64 + lane];
    }
    float o = acc / (den + 1e-16f) + bias[lane];
    o = fmaxf(o, 0.f);
    out[(size_t)n * 64 + lane] = __float2half(o);
}

// ---------------- pooling ----------------
__global__ __launch_bounds__(256) void gate_kernel(const __half* __restrict__ h,
                                                   const float* __restrict__ w1,
                                                   const float* __restrict__ b1,
                                                   const float* __restrict__ w2,
                                                   const float* __restrict__ b2,
                                                   float* __restrict__ gate, int N) {
    int n = (blockIdx.x * blockDim.x + threadIdx.x) >> 6;
    int lane = threadIdx.x & 63;
    if (n >= N) return;
    float hv = __half2float(h[(size_t)n * 64 + lane]);
    float t = b1[lane];
    for (int c = 0; c < 64; ++c) t += __shfl(hv, c) * w1[c * 64 + lane];
    t = fmaxf(t, 0.f);
    float g = t * w2[lane];
#pragma unroll
    for (int o = 32; o; o >>= 1) g += __shfl_xor(g, o);
    g += b2[0];
    if (lane == 0) gate[n] = g;
}

__global__ __launch_bounds__(256) void gmax_kernel(const float* __restrict__ gate,
                                                   const int* __restrict__ batch,
                                                   unsigned* __restrict__ gm, int N) {
    __shared__ unsigned smax[16];
    int t = threadIdx.x;
    if (t < 16) smax[t] = 0u;
    __syncthreads();
    for (int i = blockIdx.x * blockDim.x + t; i < N; i += gridDim.x * blockDim.x)
        atomicMax(&smax[batch[i]], f2o(gate[i]));
    __syncthreads();
    if (t < 16 && smax[t]) atomicMax(&gm[t], smax[t]);
}

__global__ __launch_bounds__(256) void pool_p(const float* __restrict__ gate,
                                              const unsigned* __restrict__ gm,
                                              const int* __restrict__ batch,
                                              float* __restrict__ pg,
                                              float* __restrict__ gden, int N) {
    __shared__ float part[16];
    int t = threadIdx.x;
    if (t < 16) part[t] = 0.f;
    __syncthreads();
    int n = blockIdx.x * blockDim.x + t;
    if (n < N) {
        int b = batch[n];
        unsigned u = gm[b];
        float mf = u ? o2f(u) : 0.f;
        float p = expf(gate[n] - mf);
        pg[n] = p;
        atomicAdd(&part[b], p);
    }
    __syncthreads();
    if (t < 16 && part[t] != 0.f) atomicAdd(&gden[t], part[t]);
}

#define POOL_SPLIT 32
__global__ __launch_bounds__(256) void pool_sum2(const __half* __restrict__ h,
                                                 const float* __restrict__ pg,
                                                 const int* __restrict__ gstart,
                                                 float* __restrict__ pooled, int N) {
    __shared__ float part[256];
    int g = blockIdx.x;
    int r0 = gstart[g], r1 = gstart[g + 1];
    int len = r1 - r0;
    int chunk = (len + POOL_SPLIT - 1) / POOL_SPLIT;
    int s0 = r0 + blockIdx.y * chunk;
    int s1 = min(s0 + chunk, r1);
    int wv = threadIdx.x >> 6, lane = threadIdx.x & 63;
    float acc = 0.f;
    for (int n = s0 + wv; n < s1; n += 4)
        acc += pg[n] * __half2float(h[(size_t)n * 64 + lane]);
    part[threadIdx.x] = acc;
    __syncthreads();
    if (threadIdx.x < 64) {
        float tot = part[threadIdx.x] + part[64 + threadIdx.x] +
                    part[128 + threadIdx.x] + part[192 + threadIdx.x];
        if (tot != 0.f) atomicAdd(&pooled[g * 64 + threadIdx.x], tot);
    }
}

__global__ void dec_prep(const float* __restrict__ pooled, const float* __restrict__ gden,
                         const float* __restrict__ Wd0, const float* __restrict__ asd,
                         const float* __restrict__ add, float* __restrict__ hd016,
                         float* __restrict__ es16, float* __restrict__ ed16) {
    int g = blockIdx.x;
    int lane = threadIdx.x;
    float pn = pooled[g * 64 + lane] / (gden[g] + 1e-16f);
    float o = 0.f;
    for (int c = 0; c < 64; ++c) o += __shfl(pn, c) * Wd0[c * 64 + lane];
    hd016[g * 64 + lane] = o;
    float s = o * asd[lane], d = o * add[lane];
#pragma unroll
    for (int off = 32; off; off >>= 1) {
        s += __shfl_xor(s, off);
        d += __shfl_xor(d, off);
    }
    if (lane == 0) {
        es16[g] = s;
        ed16[g] = d;
    }
}

// ---------------- host ----------------
static inline int cdiv(int a, int b) { return (a + b - 1) / b; }

extern "C" void kernel_launch(void* const* d_in, const int* in_sizes, int n_in,
                              void* d_out, int out_size, void* d_ws, size_t ws_size,
                              hipStream_t stream) {
    const float* x      = (const float*)d_in[0];
    const int*   ei     = (const int*)  d_in[1];
    const int*   batch  = (const int*)  d_in[2];
    const float* W_e0   = (const float*)d_in[3];
    const float* a_s_e0 = (const float*)d_in[4];
    const float* a_d_e0 = (const float*)d_in[5];
    const float* b_e0   = (const float*)d_in[6];
    const float* W_e1   = (const float*)d_in[7];
    const float* a_s_e1 = (const float*)d_in[8];
    const float* a_d_e1 = (const float*)d_in[9];
    const float* b_e1   = (const float*)d_in[10];
    const float* W_d0   = (const float*)d_in[11];
    const float* a_s_d0 = (const float*)d_in[12];
    const float* a_d_d0 = (const float*)d_in[13];
    const float* b_d0   = (const float*)d_in[14];
    const float* W_d1   = (const float*)d_in[15];
    const float* a_s_d1 = (const float*)d_in[16];
    const float* a_d_d1 = (const float*)d_in[17];
    const float* b_d1   = (const float*)d_in[18];
    const float* g_w1   = (const float*)d_in[19];
    const float* g_b1   = (const float*)d_in[20];
    const float* g_w2   = (const float*)d_in[21];
    const float* g_b2   = (const float*)d_in[22];

    const int N    = in_sizes[2];
    const int E    = in_sizes[1] / 2;
    const int Etot = E + N;
    const int Din  = in_sizes[0] / N;  // 128

    char* w = (char*)d_ws;
    size_t o = 0;
    auto alloc = [&](size_t bytes) -> void* {
        void* p = w + o;
        o = (o + bytes + 255) & ~(size_t)255;
        return p;
    };
    __half*   h16    = (__half*)  alloc((size_t)N * 512 * 2);  // also z (dec1)
    __half*   x16    = (__half*)  alloc((size_t)N * Din * 2);
    __half*   bufA   = (__half*)  alloc((size_t)N * 64 * 2);
    __half*   bufB   = (__half*)  alloc((size_t)N * 64 * 2);
    __half*   wt_e0  = (__half*)  alloc((size_t)512 * 128 * 2);
    __half*   wt_e1  = (__half*)  alloc((size_t)512 * 64 * 2);
    __half*   wst_d1 = (__half*)  alloc((size_t)128 * 64 * 2);
    float*    ws_e0  = (float*)   alloc(8 * 128 * 4);
    float*    wd_e0  = (float*)   alloc(8 * 128 * 4);
    float*    ws_e1  = (float*)   alloc(8 * 64 * 4);
    float*    wd_e1  = (float*)   alloc(8 * 64 * 4);
    float*    ws_d1  = (float*)   alloc(64 * 4);
    float*    wd_d1  = (float*)   alloc(64 * 4);
    float*    es     = (float*)   alloc((size_t)N * 8 * 4);
    float*    ed     = (float*)   alloc((size_t)N * 8 * 4);
    float*    gate   = (float*)   alloc((size_t)N * 4);
    float*    pg     = (float*)   alloc((size_t)N * 4);
    int*      off    = (int*)     alloc((size_t)(N + 1) * 4);
    int*      cnt    = (int*)     alloc((size_t)N * 4);
    int*      esrc   = (int*)     alloc((size_t)Etot * 4);
    int*      bsum   = (int*)     alloc(256 * 4);
    int*      gstart = (int*)     alloc(17 * 4);
    unsigned* gm     = (unsigned*)alloc(16 * 4);
    float*    gden   = (float*)   alloc(16 * 4);
    float*    pooled = (float*)   alloc(16 * 64 * 4);
    float*    hd016  = (float*)   alloc(16 * 64 * 4);
    float*    es16   = (float*)   alloc(16 * 4);
    float*    ed16   = (float*)   alloc(16 * 4);
    (void)ws_size; (void)n_in; (void)out_size;

    const int nodeWaveGrid = cdiv(N, 4);
    const int nodeThreadGrid = cdiv(N, TB);
    const int edgeGrid     = cdiv(Etot, TB);
    const int scanBlocks   = cdiv(N, 256);

    // ---- CSR + graph ranges ----
    hipMemsetAsync(cnt, 0, (size_t)N * 4, stream);
    csr_count<<<edgeGrid, TB, 0, stream>>>(ei, E, Etot, cnt);
    scan_phase1<<<scanBlocks, 256, 0, stream>>>(cnt, esrc /*temp incl*/, bsum, N);
    scan_phase2<<<1, 256, 0, stream>>>(bsum, scanBlocks);
    scan_phase3<<<scanBlocks, 256, 0, stream>>>(esrc, bsum, off, N);
    hipMemsetAsync(cnt, 0, (size_t)N * 4, stream);
    csr_fill<<<edgeGrid, TB, 0, stream>>>(ei, E, Etot, off, cnt, esrc);
    find_gstart<<<nodeThreadGrid, TB, 0, stream>>>(batch, gstart, N);

    // ---- prep ----
    cast_f2h<<<cdiv(N * Din / 2, TB), TB, 0, stream>>>(x, x16, N * Din);
    transpose_cast<<<cdiv(512 * 128, TB), TB, 0, stream>>>(W_e0, wt_e0, Din, 512);
    transpose_cast<<<cdiv(512 * 64, TB), TB, 0, stream>>>(W_e1, wt_e1, 64, 512);
    make_wstackT<<<cdiv(128 * 64, TB), TB, 0, stream>>>(W_d1, wst_d1, 64, 1, 128);
    make_ws<<<cdiv(8 * 128, TB), TB, 0, stream>>>(W_e0, a_s_e0, a_d_e0, ws_e0, wd_e0, 128, 8, 64);
    make_ws<<<cdiv(8 * 64, TB), TB, 0, stream>>>(W_e1, a_s_e1, a_d_e1, ws_e1, wd_e1, 64, 8, 64);
    make_ws<<<1, TB, 0, stream>>>(W_d1, a_s_d1, a_d_d1, ws_d1, wd_d1, 64, 1, 128);

    // ---- encoder layer 0 (H=8, relu) ----
    scores_nt<128, 8><<<nodeThreadGrid, TB, 0, stream>>>(x16, ws_e0, wd_e0, es, ed, N);
    {
        dim3 grid(512 / 64, cdiv(N, 64));
        gemm_mfma<128><<<grid, TB, 0, stream>>>(x16, wt_e0, h16, N, 512);
    }
    gat_gather_h8<true><<<nodeWaveGrid, TB, 0, stream>>>(
        h16, es, ed, off, esrc, b_e0, bufA, N);

    // ---- encoder layer 1 (H=8, no relu) ----
    scores_nt<64, 8><<<nodeThreadGrid, TB, 0, stream>>>(bufA, ws_e1, wd_e1, es, ed, N);
    {
        dim3 grid(512 / 64, cdiv(N, 64));
        gemm_mfma<64><<<grid, TB, 0, stream>>>(bufA, wt_e1, h16, N, 512);
    }
    gat_gather_h8<false><<<nodeWaveGrid, TB, 0, stream>>>(
        h16, es, ed, off, esrc, b_e1, bufB, N);

    // ---- pooling ----
    hipMemsetAsync(gm, 0, 16 * 4, stream);
    hipMemsetAsync(gden, 0, 16 * 4, stream);
    hipMemsetAsync(pooled, 0, 16 * 64 * 4, stream);
    gate_kernel<<<nodeWaveGrid, TB, 0, stream>>>(bufB, g_w1, g_b1, g_w2, g_b2, gate, N);
    gmax_kernel<<<256, TB, 0, stream>>>(gate, batch, gm, N);
    pool_p<<<nodeThreadGrid, TB, 0, stream>>>(gate, gm, batch, pg, gden, N);
    {
        dim3 grid(16, POOL_SPLIT);
        pool_sum2<<<grid, TB, 0, stream>>>(bufB, pg, gstart, pooled, N);
    }
    dec_prep<<<16, 64, 0, stream>>>(pooled, gden, W_d0, a_s_d0, a_d_d0, hd016, es16, ed16);

    // ---- decoder layer 0 (H=1, relu) ----
    gat_gather_d0<<<nodeWaveGrid, TB, 0, stream>>>(
        hd016, es16, ed16, off, esrc, batch, b_d0, bufA, N);

    // ---- decoder layer 1 (H=1, C=128, no relu): z-path -> d_out ----
    scores_nt<64, 1><<<nodeThreadGrid, TB, 0, stream>>>(bufA, ws_d1, wd_d1, es, ed, N);
    gat_gather_z<64, 1><<<nodeWaveGrid, TB, 0, stream>>>(bufA, es, ed, off, esrc, h16 /*z*/, N);
    {
        dim3 grid(2, cdiv(N, 64));
        gemm_kt<64, float, false><<<grid, TB, 0, stream>>>(h16 /*z*/, wst_d1, b_d1, (float*)d_out, N, 128);
    }
}